// Round 6
// baseline (731.516 us; speedup 1.0000x reference)
//
#include <hip/hip_runtime.h>
#include <hip/hip_bf16.h>
#include <math.h>

// Problem constants
#define Bn 4
#define Tn 4096
#define Dn 1024
#define Kn 128
#define TWOK 256
#define Hn 8
#define Mmlp 4096
#define NROW (Bn * Tn)          // 16384
#define TAPS 16                 // |lambda| <= 0.232 -> tap-16 residual ~1e-9

typedef __attribute__((ext_vector_type(8))) short bf16x8;     // 8 bf16 = 4 VGPRs
typedef __attribute__((ext_vector_type(4))) float floatx4;    // 16x16 MFMA acc
typedef __attribute__((ext_vector_type(16))) float floatx16;  // 32x32 MFMA acc

// fast sigmoid: v_exp_f32-based (__expf)
__device__ __forceinline__ float sigmoidf_(float x) { return 1.f / (1.f + __expf(-x)); }

// ---------------------------------------------------------------------------
// fp32 -> bf16 cast
// ---------------------------------------------------------------------------
__global__ __launch_bounds__(256) void f2bf_kernel(const float* __restrict__ in,
                                                   __hip_bfloat16* __restrict__ out,
                                                   int n) {
    const int i = (blockIdx.x * 256 + threadIdx.x) * 4;
    if (i >= n) return;
    const float4 v = *(const float4*)(in + i);
    out[i + 0] = __float2bfloat16(v.x);
    out[i + 1] = __float2bfloat16(v.y);
    out[i + 2] = __float2bfloat16(v.z);
    out[i + 3] = __float2bfloat16(v.w);
}

// ---------------------------------------------------------------------------
// LayerNorm (D=1024, 256 thr) -> bf16
// ---------------------------------------------------------------------------
__global__ __launch_bounds__(256) void ln_kernel(const float* __restrict__ x,
                                                 const float* __restrict__ g,
                                                 const float* __restrict__ b,
                                                 __hip_bfloat16* __restrict__ out) {
    const int row = blockIdx.x;
    const float4* xr = (const float4*)(x + (size_t)row * Dn);
    float4 v = xr[threadIdx.x];
    float s = v.x + v.y + v.z + v.w;
    float ss = v.x * v.x + v.y * v.y + v.z * v.z + v.w * v.w;
    for (int off = 32; off; off >>= 1) {
        s += __shfl_down(s, off);
        ss += __shfl_down(ss, off);
    }
    __shared__ float rs[4], rss[4];
    const int wv = threadIdx.x >> 6, ln = threadIdx.x & 63;
    if (ln == 0) { rs[wv] = s; rss[wv] = ss; }
    __syncthreads();
    s = rs[0] + rs[1] + rs[2] + rs[3];
    ss = rss[0] + rss[1] + rss[2] + rss[3];
    const float mean = s * (1.f / Dn);
    const float var = ss * (1.f / Dn) - mean * mean;
    const float inv = rsqrtf(var + 1e-5f);
    const float4 gg = ((const float4*)g)[threadIdx.x];
    const float4 bb = ((const float4*)b)[threadIdx.x];
    __hip_bfloat16* op = out + (size_t)row * Dn + threadIdx.x * 4;
    op[0] = __float2bfloat16((v.x - mean) * inv * gg.x + bb.x);
    op[1] = __float2bfloat16((v.y - mean) * inv * gg.y + bb.y);
    op[2] = __float2bfloat16((v.z - mean) * inv * gg.z + bb.z);
    op[3] = __float2bfloat16((v.w - mean) * inv * gg.w + bb.w);
}

// ---------------------------------------------------------------------------
// bf16 MFMA GEMM: C[M,N] = A[M,K] @ B[N,K]^T.  128x128 tile, BK=32, 4 waves.
// (kept for the small-N GEMMs: steps 2, 3 where N=256 -> 256-tile underfills)
// Epilogues: 0 none | 1 C=sigmoid(bias[0])*acc
// ---------------------------------------------------------------------------
template <int EPI, typename CT>
__global__ __launch_bounds__(256, 4)
void gemm_bf(const ushort* __restrict__ A,
             const ushort* __restrict__ B,
             CT* __restrict__ C,
             int M, int N, int Kd,
             const float* __restrict__ bias) {
    __shared__ ushort As[128 * 32];   // contiguous (global_load_lds requirement)
    __shared__ ushort Bs[128 * 32];
    const int tid = threadIdx.x;
    const int nbx = gridDim.x;
    const int nblk = nbx * gridDim.y;
    int bid = blockIdx.y * nbx + blockIdx.x;
    if ((nblk & 7) == 0)
        bid = (bid & 7) * (nblk >> 3) + (bid >> 3);   // XCD strip remap
    const int m0 = (bid / nbx) * 128, n0 = (bid % nbx) * 128;
    const int wave = tid >> 6, lane = tid & 63;
    const int wm = wave >> 1, wn = wave & 1;
    const int mlane = lane & 15, quad = lane >> 4;

    floatx4 acc[4][4] = {};

    {
        const ushort* Ap = A + (size_t)m0 * Kd;
        const ushort* Bp = B + (size_t)n0 * Kd;
        for (int k0 = 0; k0 < Kd; k0 += 32) {
#pragma unroll
            for (int q = 0; q < 2; ++q) {
                const int c = q * 256 + tid;          // 16B chunk: row=c>>2, kcol=(c&3)*8
                const int row = c >> 2, kc = (c & 3) * 8;
                __builtin_amdgcn_global_load_lds(
                    (const __attribute__((address_space(1))) void*)(Ap + (size_t)row * Kd + k0 + kc),
                    (__attribute__((address_space(3))) void*)(As + c * 8), 16, 0, 0);
                __builtin_amdgcn_global_load_lds(
                    (const __attribute__((address_space(1))) void*)(Bp + (size_t)row * Kd + k0 + kc),
                    (__attribute__((address_space(3))) void*)(Bs + c * 8), 16, 0, 0);
            }
            __syncthreads();
            bf16x8 af[4], bfr[4];
#pragma unroll
            for (int t = 0; t < 4; ++t) {
                af[t]  = *(const bf16x8*)&As[(wm * 64 + t * 16 + mlane) * 32 + quad * 8];
                bfr[t] = *(const bf16x8*)&Bs[(wn * 64 + t * 16 + mlane) * 32 + quad * 8];
            }
#pragma unroll
            for (int i = 0; i < 4; ++i)
#pragma unroll
                for (int j = 0; j < 4; ++j)
                    acc[i][j] = __builtin_amdgcn_mfma_f32_16x16x32_bf16(af[i], bfr[j], acc[i][j], 0, 0, 0);
            __syncthreads();
        }
    }

    float s_pre = 0.f;
    if constexpr (EPI == 1) s_pre = sigmoidf_(bias[0]);

    const int cbase = n0 + wn * 64 + mlane;
#pragma unroll
    for (int i = 0; i < 4; ++i) {
#pragma unroll
        for (int r = 0; r < 4; ++r) {
            const int row = m0 + wm * 64 + i * 16 + quad * 4 + r;
            const size_t ro = (size_t)row * N;
#pragma unroll
            for (int j = 0; j < 4; ++j) {
                const int col = cbase + j * 16;
                const float a = acc[i][j][r];
                float o;
                if constexpr (EPI == 0) o = a;
                else                    o = s_pre * a;
                if constexpr (__is_same(CT, float)) C[ro + col] = o;
                else                                C[ro + col] = __float2bfloat16(o);
            }
        }
    }
}

// ---------------------------------------------------------------------------
// 256x256-tile bf16 GEMM, v4b: 32x32x16 MFMA + register-double-buffered
// fragment prefetch, ONE barrier per K-step.
// (v4b = v4 with the An/Bn local-pointer names fixed: `Bn` collided with the
//  `#define Bn 4` problem constant, macro-expanding the pointer into the int
//  literal 4 -> the round-4/5 compile failure.  No functional change.)
//
// C[M,N] = A[M,K] @ B[N,K]^T.  BK=64, 8 waves (2Mx4N), 128 KiB LDS K-step
// double-buffer, XOR-octet LDS swizzle (write-side pre-swizzled global src,
// read-side (2ks+lhi)^(row&7); conflict-free), 2-D XCD chunk remap.
//
// Why: r1(m201-style phases) and r3(unpinned) both sat at 31% MfmaUtil --
// in a barrier-locked phase the CU-wide ds_read burst serializes with the
// MFMA cluster by construction.  v4 makes the overlap an ILP property:
// each K-step is 4 quarters (K=16); quarter q issues the 6 ds_reads of
// quarter q+1 into the ALTERNATE register set, then runs 8 MFMAs on the
// current set -> MFMAs never wait on same-quarter reads; LDS pipe and
// matrix pipe run concurrently.  32x32x16 runs at ~99.8% of peak (m119)
// vs ~87% for 16x16x32, and halves MFMA instruction count.
//
// Hazard chain (formal, 1 barrier + 1 lgkmcnt + 1 vmcnt per K-step):
//   WAR buf[t&1]:  all reads drained (lgkmcnt(0)) -> s_barrier ->
//                  stage(t+2) issue.
//   RAW buf[(t+1)&1]: own stage(t+1) landed (vmcnt(0), issued a full K-step
//                  earlier so the wait is cheap) -> s_barrier (=> ALL
//                  waves' stages landed) -> reads of next K-step.
// Fragment layouts (gfx950, HW-verified m74/m101 for C/D):
//   A: lane holds A[row=l&31][k=8*(l>>5)+j]  (16B contiguous -> b128)
//   B^T storage: identical form.  C/D: col=l&31, row=(r&3)+8*(r>>2)+4*(l>>5).
// Requirements: M,N % 256 == 0, K % 64 == 0, K >= 128.
// Epilogues: 0 C=acc | 2 C=aux1+sig(acc+bias)*aux2 | 3 C=silu(acc+bias)
//            | 4 C=acc+bias+aux1
// ---------------------------------------------------------------------------
template <int EPI, typename CT>
__global__ __launch_bounds__(512, 2)
void gemm256(const ushort* __restrict__ A, const ushort* __restrict__ B,
             CT* __restrict__ C, int N, int Kd,
             const float* __restrict__ bias, const float* __restrict__ aux1,
             const __hip_bfloat16* __restrict__ aux2, int cg) {
    __shared__ ushort As[2][256 * 64];   // 64 KiB
    __shared__ ushort Bs[2][256 * 64];   // 64 KiB
    const int tid = threadIdx.x;
    const int nbx = gridDim.x;
    const int nblk = nbx * gridDim.y;
    const int nrows = nblk / nbx;
    int bid = blockIdx.y * nbx + blockIdx.x;
    int mt, ntile;
    if ((nblk & 7) == 0 && cg > 0 && nbx % cg == 0 && nrows % (8 / cg) == 0) {
        // 2-D chunk per XCD: rows split into 8/cg groups, cols into cg groups
        const int xcd = bid & 7, i = bid >> 3;
        const int cPerG = nbx / cg;
        const int rPerG = nrows / (8 / cg);
        const int rg = xcd / cg, cgi = xcd % cg;
        mt = rg * rPerG + i / cPerG;
        ntile = cgi * cPerG + i % cPerG;
    } else {
        mt = bid / nbx; ntile = bid % nbx;
    }
    const int m0 = mt * 256, n0 = ntile * 256;
    const int wave = tid >> 6, lane = tid & 63;
    const int wm = wave >> 2, wn = wave & 3;          // 2 x 4 wave grid
    const int l31 = lane & 31, lhi = lane >> 5, l7 = lane & 7;
    const int NT = Kd >> 6;                           // K-steps of 64 (NT >= 2)

    // staging map: thread covers row r0+(tid>>3), element-octet (tid&7)^(row&7)
    const int srow = tid >> 3;
    const ushort* Agbase = A + (size_t)m0 * Kd + (size_t)srow * Kd +
                           (size_t)(((tid & 7) ^ (srow & 7)) << 3);
    const ushort* Bgbase = B + (size_t)n0 * Kd + (size_t)srow * Kd +
                           (size_t)(((tid & 7) ^ (srow & 7)) << 3);

    auto stA = [&](int s, int half) {   // half 0: rows {0-63,128-191}; 1: +64
        const int r0 = half * 64;
        const ushort* g = Agbase + (size_t)r0 * Kd + (s << 6);
        ushort* l = &As[s & 1][(r0 << 6) + (tid << 3)];
        __builtin_amdgcn_global_load_lds(
            (const __attribute__((address_space(1))) void*)g,
            (__attribute__((address_space(3))) void*)l, 16, 0, 0);
        __builtin_amdgcn_global_load_lds(
            (const __attribute__((address_space(1))) void*)(g + (size_t)128 * Kd),
            (__attribute__((address_space(3))) void*)(l + (128 << 6)), 16, 0, 0);
    };
    auto stB = [&](int s, int half) {   // half 0: rows 0-127; 1: rows 128-255
        const int r0 = half * 128;
        const ushort* g = Bgbase + (size_t)r0 * Kd + (s << 6);
        ushort* l = &Bs[s & 1][(r0 << 6) + (tid << 3)];
        __builtin_amdgcn_global_load_lds(
            (const __attribute__((address_space(1))) void*)g,
            (__attribute__((address_space(3))) void*)l, 16, 0, 0);
        __builtin_amdgcn_global_load_lds(
            (const __attribute__((address_space(1))) void*)(g + (size_t)64 * Kd),
            (__attribute__((address_space(3))) void*)(l + (64 << 6)), 16, 0, 0);
    };

    floatx16 acc[4][2] = {};
    bf16x8 sa[2][4], sb[2][2];        // two fragment sets (register dbuf)

    const int arow = (wm * 128 + l31) << 6;   // ushort idx of A frag row base
    const int brow = (wn * 64 + l31) << 6;
    // swizzled octet offsets per ksub: ((2*ks + lhi) ^ l7) * 8 ushorts
    int oq[4];
#pragma unroll
    for (int ks = 0; ks < 4; ++ks) oq[ks] = ((((ks << 1) + lhi) ^ l7) << 3);

#define RD(S, KS, BA, BB)                                                  \
    {                                                                      \
        _Pragma("unroll")                                                  \
        for (int mb_ = 0; mb_ < 4; ++mb_)                                  \
            sa[S][mb_] = *(const bf16x8*)(BA + arow + mb_ * 2048 + oq[KS]);\
        _Pragma("unroll")                                                  \
        for (int nb_ = 0; nb_ < 2; ++nb_)                                  \
            sb[S][nb_] = *(const bf16x8*)(BB + brow + nb_ * 2048 + oq[KS]);\
    }

#define MM(S)                                                              \
    __builtin_amdgcn_s_setprio(1);                                         \
    _Pragma("unroll")                                                      \
    for (int mb_ = 0; mb_ < 4; ++mb_) {                                    \
        _Pragma("unroll")                                                  \
        for (int nb_ = 0; nb_ < 2; ++nb_) {                                \
            acc[mb_][nb_] = __builtin_amdgcn_mfma_f32_32x32x16_bf16(       \
                sa[S][mb_], sb[S][nb_], acc[mb_][nb_], 0, 0, 0);           \
        }                                                                  \
    }                                                                      \
    __builtin_amdgcn_s_setprio(0);

    // prologue: stage steps 0 and 1, wait step 0, read ksub0(0) into set 0
    stA(0, 0); stA(0, 1); stB(0, 0); stB(0, 1);
    stA(1, 0); stA(1, 1); stB(1, 0); stB(1, 1);
    asm volatile("s_waitcnt vmcnt(8)" ::: "memory");   // step 0 landed
    __builtin_amdgcn_s_barrier();                      // => all waves' step 0 landed
    {
        const ushort* Acur = &As[0][0];
        const ushort* Bcur = &Bs[0][0];
        RD(0, 0, Acur, Bcur)
    }

    for (int t = 0; t < NT; ++t) {
        const ushort* Acur = &As[t & 1][0];
        const ushort* Bcur = &Bs[t & 1][0];
        const ushort* Anxt = &As[(t + 1) & 1][0];
        const ushort* Bnxt = &Bs[(t + 1) & 1][0];
        // q0: read ksub1 -> set1, compute ksub0 (set0)
        RD(1, 1, Acur, Bcur)
        MM(0)
        // q1: read ksub2 -> set0, compute ksub1 (set1)
        RD(0, 2, Acur, Bcur)
        MM(1)
        // q2: read ksub3 -> set1, compute ksub2 (set0)
        RD(1, 3, Acur, Bcur)
        MM(0)
        // q3: sync point; stage step t+2; read ksub0(t+1); compute ksub3
        asm volatile("s_waitcnt lgkmcnt(0)" ::: "memory");     // my buf[t&1] reads drained
        if (t + 1 < NT)
            asm volatile("s_waitcnt vmcnt(0)" ::: "memory");   // stage(t+1) landed (issued ~1 K-step ago)
        __builtin_amdgcn_s_barrier();                          // all waves drained+landed
        if (t + 2 < NT) { stA(t + 2, 0); stA(t + 2, 1); stB(t + 2, 0); stB(t + 2, 1); }
        if (t + 1 < NT) RD(0, 0, Anxt, Bnxt)
        MM(1)
    }
#undef RD
#undef MM

    // epilogue: 32x32 C/D layout: col = l31, row = (r&3) + 8*(r>>2) + 4*lhi
    const int cb0 = n0 + wn * 64 + l31;
#pragma unroll
    for (int mb = 0; mb < 4; ++mb) {
#pragma unroll
        for (int nb = 0; nb < 2; ++nb) {
            const int col = cb0 + nb * 32;
#pragma unroll
            for (int r = 0; r < 16; ++r) {
                const int row = m0 + wm * 128 + mb * 32 + (r & 3) + 8 * (r >> 2) + 4 * lhi;
                const size_t ro = (size_t)row * N;
                const float av = acc[mb][nb][r];
                float o;
                if constexpr (EPI == 0) {
                    o = av;
                } else if constexpr (EPI == 2) {
                    o = aux1[ro + col] + sigmoidf_(av + bias[col]) * __bfloat162float(aux2[ro + col]);
                } else if constexpr (EPI == 3) {
                    const float tt = av + bias[col];
                    o = tt * sigmoidf_(tt);
                } else {  // 4
                    o = av + bias[col] + aux1[ro + col];
                }
                if constexpr (__is_same(CT, float)) C[ro + col] = o;
                else                                C[ro + col] = __float2bfloat16(o);
            }
        }
    }
}

// ---------------------------------------------------------------------------
// Fused: depthwise causal conv(4) + bias + SiLU + memory injection + 16-tap
// complex FIR + per-head coupling -> eig (fp32 out) + eig_bf (bf16 operand).
// ---------------------------------------------------------------------------
#define TCH 256
#define BROWS (TCH + TAPS + 2)   // beta rows: t in [t0-18, t0+255] = 274
#define UROWS (TCH + TAPS - 1)   // u rows:    t in [t0-15, t0+255] = 271

__global__ __launch_bounds__(256) void cfc_kernel(const float* __restrict__ beta,
                                                  const float* __restrict__ mgp,
                                                  const float* __restrict__ conv_w,
                                                  const float* __restrict__ conv_b,
                                                  const float* __restrict__ log_decay,
                                                  const float* __restrict__ freq,
                                                  const float* __restrict__ coup,
                                                  float* __restrict__ eig,
                                                  __hip_bfloat16* __restrict__ eig_bf) {
    const int b = blockIdx.z, h = blockIdx.y, t0 = blockIdx.x * TCH;
    const int tid = threadIdx.x;

    __shared__ float sbeta[BROWS * 32];       // col cg: cg<16 -> real ch, else imag
    __shared__ float su[UROWS * 33];
    __shared__ float str[16 * TAPS], sti[16 * TAPS];
    __shared__ float scoup[16 * 16];
    __shared__ float scw[32 * 4], scb[32];

    auto chan = [&](int cg) { return (cg < 16) ? (h * 16 + cg) : (128 + h * 16 + cg - 16); };

    for (int idx = tid; idx < BROWS * 32; idx += 256) {
        const int r = idx >> 5, cg = idx & 31;
        const int t = t0 - (TAPS + 2) + r;
        sbeta[idx] = (t >= 0) ? beta[((size_t)b * Tn + t) * TWOK + chan(cg)] : 0.f;
    }
    for (int idx = tid; idx < UROWS * 32; idx += 256) {
        const int r = idx >> 5, cg = idx & 31;
        const int t = t0 - (TAPS - 1) + r;
        su[r * 33 + cg] = (t >= 0) ? mgp[((size_t)b * Tn + t) * TWOK + chan(cg)] : 0.f;
    }
    if (tid < 128) scw[tid] = conv_w[chan(tid >> 2) * 4 + (tid & 3)];
    else if (tid < 160) scb[tid - 128] = conv_b[chan(tid - 128)];
    scoup[tid] = coup[h * 256 + tid];
    {
        const int k = tid >> 4, d = tid & (TAPS - 1);
        const float mag = sigmoidf_(log_decay[h * 16 + k]);
        const float f = freq[h * 16 + k];
        const float p = powf(mag, (float)d);
        str[k * TAPS + d] = p * cosf(d * f);
        sti[k * TAPS + d] = p * sinf(d * f);
    }
    __syncthreads();

    for (int idx = tid; idx < UROWS * 32; idx += 256) {
        const int r = idx >> 5, cg = idx & 31;
        const int rb = r + 3;
        float v = sbeta[(rb - 3) * 32 + cg] * scw[cg * 4 + 0] +
                  sbeta[(rb - 2) * 32 + cg] * scw[cg * 4 + 1] +
                  sbeta[(rb - 1) * 32 + cg] * scw[cg * 4 + 2] +
                  sbeta[(rb - 0) * 32 + cg] * scw[cg * 4 + 3] + scb[cg];
        v = v * sigmoidf_(v);
        su[r * 33 + cg] += v;
    }
    __syncthreads();

    const int ru = tid + (TAPS - 1);
    float orr[16], oii[16];
#pragma unroll
    for (int j = 0; j < 16; ++j) { orr[j] = 0.f; oii[j] = 0.f; }
#pragma unroll 4
    for (int k = 0; k < 16; ++k) {
        float accr = 0.f, acci = 0.f;
#pragma unroll
        for (int d = 0; d < TAPS; ++d) {
            const float ur = su[(ru - d) * 33 + k];
            const float ui = su[(ru - d) * 33 + 16 + k];
            const float lr = str[k * TAPS + d], li = sti[k * TAPS + d];
            accr += lr * ur - li * ui;
            acci += lr * ui + li * ur;
        }
#pragma unroll
        for (int j = 0; j < 16; ++j) {
            orr[j] += scoup[j * 16 + k] * accr;
            oii[j] += scoup[j * 16 + k] * acci;
        }
    }
    const size_t base = ((size_t)b * Tn + t0 + tid) * TWOK + h * 16;
    float4* er = (float4*)(eig + base);
    float4* ei = (float4*)(eig + base + Kn);
#pragma unroll
    for (int q = 0; q < 4; ++q) {
        er[q] = make_float4(orr[4 * q], orr[4 * q + 1], orr[4 * q + 2], orr[4 * q + 3]);
        ei[q] = make_float4(oii[4 * q], oii[4 * q + 1], oii[4 * q + 2], oii[4 * q + 3]);
    }
#pragma unroll
    for (int j = 0; j < 16; ++j) {
        eig_bf[base + j] = __float2bfloat16(orr[j]);
        eig_bf[base + Kn + j] = __float2bfloat16(oii[j]);
    }
}

// ---------------------------------------------------------------------------
extern "C" void kernel_launch(void* const* d_in, const int* in_sizes, int n_in,
                              void* d_out, int out_size, void* d_ws, size_t ws_size,
                              hipStream_t stream) {
    const float* x          = (const float*)d_in[0];
    const float* prev_eig   = (const float*)d_in[1];
    const float* in_proj_w  = (const float*)d_in[2];
    const float* conv_w     = (const float*)d_in[3];
    const float* conv_b     = (const float*)d_in[4];
    const float* mem_gate   = (const float*)d_in[5];
    const float* mem_proj_w = (const float*)d_in[6];
    const float* log_decay  = (const float*)d_in[7];
    const float* frequency  = (const float*)d_in[8];
    const float* coupling   = (const float*)d_in[9];
    const float* out_proj_w = (const float*)d_in[10];
    const float* gate_w     = (const float*)d_in[11];
    const float* gate_b     = (const float*)d_in[12];
    const float* mlp_w1     = (const float*)d_in[13];
    const float* mlp_b1     = (const float*)d_in[14];
    const float* mlp_w2     = (const float*)d_in[15];
    const float* mlp_b2     = (const float*)d_in[16];
    const float* n1_g       = (const float*)d_in[17];
    const float* n1_b       = (const float*)d_in[18];
    const float* n2_g       = (const float*)d_in[19];
    const float* n2_b       = (const float*)d_in[20];

    float* out = (float*)d_out;                     // x2 [16384,1024]
    float* eig = out + (size_t)NROW * Dn;           // eig [16384,256] fp32

    char* wsb = (char*)d_ws;
    const size_t MB = 1 << 20;
    const bool bigws = ws_size >= 252 * MB;

    float* x1    = (float*)(wsb + 0);               // 64MB, live step8..end
    float* beta  = (float*)(wsb + 0);               //  alias, live 2-4
    float* mgp   = (float*)(wsb + 16 * MB);         //  live 3-4
    __hip_bfloat16 *h1, *eig_bf, *peig_bf, *xn_bf, *y_bf, *w1_bf, *w2_bf,
                   *gate_bf, *inpj_bf, *outpj_bf, *mempj_bf;
    if (bigws) {
        h1       = (__hip_bfloat16*)(wsb + 64 * MB);    // step 7 oproj (32MB) then step10 h1 (128MB)
        xn_bf    = (__hip_bfloat16*)(wsb + 192 * MB);   // live 1..8
        y_bf     = (__hip_bfloat16*)(wsb + 192 * MB);   //  alias (written step 9)
        w1_bf    = (__hip_bfloat16*)(wsb + 224 * MB);
        w2_bf    = (__hip_bfloat16*)(wsb + 232 * MB);
        gate_bf  = (__hip_bfloat16*)(wsb + 240 * MB);
        inpj_bf  = (__hip_bfloat16*)(wsb + 242 * MB);
        outpj_bf = (__hip_bfloat16*)(wsb + 242 * MB + 512 * 1024);
        mempj_bf = (__hip_bfloat16*)(wsb + 243 * MB);
        peig_bf  = (__hip_bfloat16*)(wsb + 244 * MB);   // live step 3 only
        eig_bf   = (__hip_bfloat16*)(wsb + 244 * MB);   //  alias (written step 4-6)
    } else {
        h1       = (__hip_bfloat16*)(wsb + 64 * MB);    // step 7 oproj (32MB) / step10 chunk h1
        eig_bf   = (__hip_bfloat16*)(wsb + 96 * MB);
        peig_bf  = (__hip_bfloat16*)(wsb + 104 * MB);
        xn_bf    = (__hip_bfloat16*)(wsb + 128 * MB);
        y_bf     = (__hip_bfloat16*)(wsb + 160 * MB);
        w1_bf    = (__hip_bfloat16*)(wsb + 192 * MB);
        w2_bf    = (__hip_bfloat16*)(wsb + 200 * MB);
        gate_bf  = (__hip_bfloat16*)(wsb + 208 * MB);
        inpj_bf  = (__hip_bfloat16*)(wsb + 210 * MB);
        outpj_bf = (__hip_bfloat16*)(wsb + 210 * MB + 512 * 1024);
        mempj_bf = (__hip_bfloat16*)(wsb + 211 * MB);
    }

    auto cvt = [&](const float* src, __hip_bfloat16* dst, int n) {
        f2bf_kernel<<<dim3((n / 4 + 255) / 256), dim3(256), 0, stream>>>(src, dst, n);
    };
    cvt(in_proj_w,  inpj_bf,  TWOK * Dn);
    cvt(mem_proj_w, mempj_bf, TWOK * TWOK);
    cvt(out_proj_w, outpj_bf, Dn * TWOK);
    cvt(gate_w,     gate_bf,  Dn * Dn);
    cvt(mlp_w1,     w1_bf,    Mmlp * Dn);
    cvt(mlp_w2,     w2_bf,    Dn * Mmlp);
    cvt(prev_eig,   peig_bf,  NROW * TWOK);

    // 1) xn = LN1(x) -> bf16
    ln_kernel<<<dim3(NROW), dim3(256), 0, stream>>>(x, n1_g, n1_b, xn_bf);
    // 2) beta = xn @ in_proj^T  [16384,256] fp32
    gemm_bf<0, float><<<dim3(2, 128), dim3(256), 0, stream>>>(
        (const ushort*)xn_bf, (const ushort*)inpj_bf, beta, NROW, TWOK, Dn, nullptr);
    // 3) mgp = sigmoid(mem_gate) * (prev_eig @ mem_proj^T)
    gemm_bf<1, float><<<dim3(2, 128), dim3(256), 0, stream>>>(
        (const ushort*)peig_bf, (const ushort*)mempj_bf, mgp, NROW, TWOK, TWOK, mem_gate);
    // 4-6) fused conv + SiLU + mem + FIR + coupling -> eig, eig_bf
    cfc_kernel<<<dim3(Tn / TCH, Hn, Bn), dim3(256), 0, stream>>>(
        beta, mgp, conv_w, conv_b, log_decay, frequency, coupling, eig, eig_bf);
    // 7) oproj = eig @ out_proj^T  [16384,1024] -> bf16 temp in h1 region
    gemm256<0, __hip_bfloat16><<<dim3(4, 64), dim3(512), 0, stream>>>(
        (const ushort*)eig_bf, (const ushort*)outpj_bf, h1, Dn, TWOK,
        nullptr, nullptr, nullptr, 2);
    // 8) x1 = x + sigmoid(xn@gate_w^T + gate_b) * oproj
    gemm256<2, float><<<dim3(4, 64), dim3(512), 0, stream>>>(
        (const ushort*)xn_bf, (const ushort*)gate_bf, x1, Dn, Dn,
        gate_b, x, h1, 2);
    // 9) y = LN2(x1) -> bf16
    ln_kernel<<<dim3(NROW), dim3(256), 0, stream>>>(x1, n2_g, n2_b, y_bf);
    // 10) MLP via 256^2 GEMMs
    if (bigws) {
        gemm256<3, __hip_bfloat16><<<dim3(16, 64), dim3(512), 0, stream>>>(
            (const ushort*)y_bf, (const ushort*)w1_bf, h1, Mmlp, Dn,
            mlp_b1, nullptr, nullptr, 2);
        gemm256<4, float><<<dim3(4, 64), dim3(512), 0, stream>>>(
            (const ushort*)h1, (const ushort*)w2_bf, out, Dn, Mmlp,
            mlp_b2, x1, nullptr, 2);
    } else {
        for (int ck = 0; ck < 2; ++ck) {
            const size_t roff = (size_t)ck * 8192 * Dn;
            gemm256<3, __hip_bfloat16><<<dim3(16, 32), dim3(512), 0, stream>>>(
                (const ushort*)(y_bf + roff), (const ushort*)w1_bf, h1, Mmlp, Dn,
                mlp_b1, nullptr, nullptr, 2);
            gemm256<4, float><<<dim3(4, 32), dim3(512), 0, stream>>>(
                (const ushort*)h1, (const ushort*)w2_bf, out + roff, Dn, Mmlp,
                mlp_b2, x1 + roff, nullptr, 2);
        }
    }
}

// Round 7
// 714.042 us; speedup vs baseline: 1.0245x; 1.0245x over previous
//
#include <hip/hip_runtime.h>
#include <hip/hip_bf16.h>
#include <math.h>

// Problem constants
#define Bn 4
#define Tn 4096
#define Dn 1024
#define Kn 128
#define TWOK 256
#define Hn 8
#define Mmlp 4096
#define NROW (Bn * Tn)          // 16384
#define TAPS 16                 // |lambda| <= 0.232 -> tap-16 residual ~1e-9

typedef __attribute__((ext_vector_type(8))) short bf16x8;     // 8 bf16 = 4 VGPRs
typedef __attribute__((ext_vector_type(4))) float floatx4;    // 16x16 MFMA acc

// fast sigmoid: v_exp_f32-based (__expf)
__device__ __forceinline__ float sigmoidf_(float x) { return 1.f / (1.f + __expf(-x)); }

// ---------------------------------------------------------------------------
// fp32 -> bf16 cast
// ---------------------------------------------------------------------------
__global__ __launch_bounds__(256) void f2bf_kernel(const float* __restrict__ in,
                                                   __hip_bfloat16* __restrict__ out,
                                                   int n) {
    const int i = (blockIdx.x * 256 + threadIdx.x) * 4;
    if (i >= n) return;
    const float4 v = *(const float4*)(in + i);
    out[i + 0] = __float2bfloat16(v.x);
    out[i + 1] = __float2bfloat16(v.y);
    out[i + 2] = __float2bfloat16(v.z);
    out[i + 3] = __float2bfloat16(v.w);
}

// ---------------------------------------------------------------------------
// LayerNorm (D=1024, 256 thr) -> bf16
// ---------------------------------------------------------------------------
__global__ __launch_bounds__(256) void ln_kernel(const float* __restrict__ x,
                                                 const float* __restrict__ g,
                                                 const float* __restrict__ b,
                                                 __hip_bfloat16* __restrict__ out) {
    const int row = blockIdx.x;
    const float4* xr = (const float4*)(x + (size_t)row * Dn);
    float4 v = xr[threadIdx.x];
    float s = v.x + v.y + v.z + v.w;
    float ss = v.x * v.x + v.y * v.y + v.z * v.z + v.w * v.w;
    for (int off = 32; off; off >>= 1) {
        s += __shfl_down(s, off);
        ss += __shfl_down(ss, off);
    }
    __shared__ float rs[4], rss[4];
    const int wv = threadIdx.x >> 6, ln = threadIdx.x & 63;
    if (ln == 0) { rs[wv] = s; rss[wv] = ss; }
    __syncthreads();
    s = rs[0] + rs[1] + rs[2] + rs[3];
    ss = rss[0] + rss[1] + rss[2] + rss[3];
    const float mean = s * (1.f / Dn);
    const float var = ss * (1.f / Dn) - mean * mean;
    const float inv = rsqrtf(var + 1e-5f);
    const float4 gg = ((const float4*)g)[threadIdx.x];
    const float4 bb = ((const float4*)b)[threadIdx.x];
    __hip_bfloat16* op = out + (size_t)row * Dn + threadIdx.x * 4;
    op[0] = __float2bfloat16((v.x - mean) * inv * gg.x + bb.x);
    op[1] = __float2bfloat16((v.y - mean) * inv * gg.y + bb.y);
    op[2] = __float2bfloat16((v.z - mean) * inv * gg.z + bb.z);
    op[3] = __float2bfloat16((v.w - mean) * inv * gg.w + bb.w);
}

// ---------------------------------------------------------------------------
// bf16 MFMA GEMM: C[M,N] = A[M,K] @ B[N,K]^T.  128x128 tile, BK=32, 4 waves.
// (kept for the small-N GEMMs: steps 2, 3 where N=256)
// Epilogues: 0 none | 1 C=sigmoid(bias[0])*acc
// ---------------------------------------------------------------------------
template <int EPI, typename CT>
__global__ __launch_bounds__(256, 4)
void gemm_bf(const ushort* __restrict__ A,
             const ushort* __restrict__ B,
             CT* __restrict__ C,
             int M, int N, int Kd,
             const float* __restrict__ bias) {
    __shared__ ushort As[128 * 32];   // contiguous (global_load_lds requirement)
    __shared__ ushort Bs[128 * 32];
    const int tid = threadIdx.x;
    const int nbx = gridDim.x;
    const int nblk = nbx * gridDim.y;
    int bid = blockIdx.y * nbx + blockIdx.x;
    if ((nblk & 7) == 0)
        bid = (bid & 7) * (nblk >> 3) + (bid >> 3);   // XCD strip remap
    const int m0 = (bid / nbx) * 128, n0 = (bid % nbx) * 128;
    const int wave = tid >> 6, lane = tid & 63;
    const int wm = wave >> 1, wn = wave & 1;
    const int mlane = lane & 15, quad = lane >> 4;

    floatx4 acc[4][4] = {};

    {
        const ushort* Ap = A + (size_t)m0 * Kd;
        const ushort* Bp = B + (size_t)n0 * Kd;
        for (int k0 = 0; k0 < Kd; k0 += 32) {
#pragma unroll
            for (int q = 0; q < 2; ++q) {
                const int c = q * 256 + tid;          // 16B chunk: row=c>>2, kcol=(c&3)*8
                const int row = c >> 2, kc = (c & 3) * 8;
                __builtin_amdgcn_global_load_lds(
                    (const __attribute__((address_space(1))) void*)(Ap + (size_t)row * Kd + k0 + kc),
                    (__attribute__((address_space(3))) void*)(As + c * 8), 16, 0, 0);
                __builtin_amdgcn_global_load_lds(
                    (const __attribute__((address_space(1))) void*)(Bp + (size_t)row * Kd + k0 + kc),
                    (__attribute__((address_space(3))) void*)(Bs + c * 8), 16, 0, 0);
            }
            __syncthreads();
            bf16x8 af[4], bfr[4];
#pragma unroll
            for (int t = 0; t < 4; ++t) {
                af[t]  = *(const bf16x8*)&As[(wm * 64 + t * 16 + mlane) * 32 + quad * 8];
                bfr[t] = *(const bf16x8*)&Bs[(wn * 64 + t * 16 + mlane) * 32 + quad * 8];
            }
#pragma unroll
            for (int i = 0; i < 4; ++i)
#pragma unroll
                for (int j = 0; j < 4; ++j)
                    acc[i][j] = __builtin_amdgcn_mfma_f32_16x16x32_bf16(af[i], bfr[j], acc[i][j], 0, 0, 0);
            __syncthreads();
        }
    }

    float s_pre = 0.f;
    if constexpr (EPI == 1) s_pre = sigmoidf_(bias[0]);

    const int cbase = n0 + wn * 64 + mlane;
#pragma unroll
    for (int i = 0; i < 4; ++i) {
#pragma unroll
        for (int r = 0; r < 4; ++r) {
            const int row = m0 + wm * 64 + i * 16 + quad * 4 + r;
            const size_t ro = (size_t)row * N;
#pragma unroll
            for (int j = 0; j < 4; ++j) {
                const int col = cbase + j * 16;
                const float a = acc[i][j][r];
                float o;
                if constexpr (EPI == 0) o = a;
                else                    o = s_pre * a;
                if constexpr (__is_same(CT, float)) C[ro + col] = o;
                else                                C[ro + col] = __float2bfloat16(o);
            }
        }
    }
}

// ---------------------------------------------------------------------------
// gemmW: 256x128-tile bf16 GEMM, 8 waves (4M x 2N, square 64x64 per wave),
// BK=32, SINGLE-buffer 24 KiB LDS, m97-style 2-barrier loop (no inline asm;
// compiler-inserted waitcnts -- the harness-proven gemm_bf body).
//
// Why (r6 post-mortem): three schedules (8-phase counted-vmcnt, unpinned,
// reg-dbuf 32x32) ALL pinned at 31% MfmaUtil.  The invariant was 128 KiB
// LDS -> 1 block/CU -> every barrier is a CU-wide convoy with no independent
// waves to cover it (m233: ~72% overhead in exactly this regime).  m97 gets
// its 37% from MULTIPLE blocks/CU overlapping across independent barrier
// domains (m114), and m132 shows occupancy loss collapses throughput.
// gemmW: 24 KiB LDS + ~116 unified regs/wave (acc 64 + frags 32 + addr)
// -> 16 waves/CU = 2 independent blocks/CU (__launch_bounds__(512,4)).
// Per-CU per K-step-pair: matrix ~1030 cy, LDS 128 b128 ~1030 cy, staging
// 48 KB ~860 cy -- balanced, inter-block overlapped.
//
// LDS bank conflicts (gemm_bf's known 8-way, 8.4M in r0): 2-bit octet
// swizzle oct ^= (row>>1)&3, applied BOTH on the global source of
// global_load_lds (LDS dest stays linear) and the ds_read octet (rule 21).
// Read side: row = 16*W + mlane -> (row>>1)&3 == (mlane>>1)&3 (lane-const).
// 16-lane group check: (row parity, swizzled octet) pairs repeat exactly
// 2x across mlane 0..15 -> 2 lanes/bank-quad = free.
// Requirements: M % 256 == 0, N % 128 == 0, K % 32 == 0.
// Epilogues: 0 C=acc | 2 C=aux1+sig(acc+bias)*aux2 | 3 C=silu(acc+bias)
//            | 4 C=acc+bias+aux1
// ---------------------------------------------------------------------------
template <int EPI, typename CT>
__global__ __launch_bounds__(512, 4)
void gemmW(const ushort* __restrict__ A, const ushort* __restrict__ B,
           CT* __restrict__ C, int N, int Kd,
           const float* __restrict__ bias, const float* __restrict__ aux1,
           const __hip_bfloat16* __restrict__ aux2, int cg) {
    __shared__ ushort As[256 * 32];   // 16 KiB
    __shared__ ushort Bs[128 * 32];   //  8 KiB
    const int tid = threadIdx.x;
    const int nbx = gridDim.x;
    const int nblk = nbx * gridDim.y;
    const int nrows = nblk / nbx;
    int bid = blockIdx.y * nbx + blockIdx.x;
    int mt, ntile;
    if ((nblk & 7) == 0 && cg > 0 && nbx % cg == 0 && nrows % (8 / cg) == 0) {
        // 2-D chunk per XCD: rows split into 8/cg groups, cols into cg groups
        const int xcd = bid & 7, i = bid >> 3;
        const int cPerG = nbx / cg;
        const int rPerG = nrows / (8 / cg);
        const int rg = xcd / cg, cgi = xcd % cg;
        mt = rg * rPerG + i / cPerG;
        ntile = cgi * cPerG + i % cPerG;
    } else {
        mt = bid / nbx; ntile = bid % nbx;
    }
    const int m0 = mt * 256, n0 = ntile * 128;
    const int wave = tid >> 6, lane = tid & 63;
    const int wm = wave >> 1, wn = wave & 1;          // 4M x 2N wave grid
    const int mlane = lane & 15, quad = lane >> 4;
    // swizzled read octet (lane-constant): quad ^ ((mlane>>1)&3)
    const int oswz = (quad ^ ((mlane >> 1) & 3)) * 8;

    floatx4 acc[4][4] = {};

    {
        const ushort* Ap = A + (size_t)m0 * Kd;
        const ushort* Bp = B + (size_t)n0 * Kd;
        // precompute per-thread staging rows/octets (swizzled global source)
        const int cB = tid, rB = cB >> 2;
        const int oB = ((cB & 3) ^ ((rB >> 1) & 3)) * 8;
        for (int k0 = 0; k0 < Kd; k0 += 32) {
#pragma unroll
            for (int q = 0; q < 2; ++q) {
                const int cA = q * 512 + tid;         // A: 1024 chunks of 16B
                const int rA = cA >> 2;
                const int oA = ((cA & 3) ^ ((rA >> 1) & 3)) * 8;
                __builtin_amdgcn_global_load_lds(
                    (const __attribute__((address_space(1))) void*)(Ap + (size_t)rA * Kd + k0 + oA),
                    (__attribute__((address_space(3))) void*)(As + cA * 8), 16, 0, 0);
            }
            __builtin_amdgcn_global_load_lds(
                (const __attribute__((address_space(1))) void*)(Bp + (size_t)rB * Kd + k0 + oB),
                (__attribute__((address_space(3))) void*)(Bs + cB * 8), 16, 0, 0);
            __syncthreads();
            bf16x8 af[4], bfr[4];
#pragma unroll
            for (int t = 0; t < 4; ++t) {
                af[t]  = *(const bf16x8*)&As[(wm * 64 + t * 16 + mlane) * 32 + oswz];
                bfr[t] = *(const bf16x8*)&Bs[(wn * 64 + t * 16 + mlane) * 32 + oswz];
            }
#pragma unroll
            for (int i = 0; i < 4; ++i)
#pragma unroll
                for (int j = 0; j < 4; ++j)
                    acc[i][j] = __builtin_amdgcn_mfma_f32_16x16x32_bf16(af[i], bfr[j], acc[i][j], 0, 0, 0);
            __syncthreads();
        }
    }

    // epilogue: 16x16 C/D layout (harness-verified): col=mlane, row=quad*4+r
    const int cbase = n0 + wn * 64 + mlane;
#pragma unroll
    for (int i = 0; i < 4; ++i) {
#pragma unroll
        for (int r = 0; r < 4; ++r) {
            const int row = m0 + wm * 64 + i * 16 + quad * 4 + r;
            const size_t ro = (size_t)row * N;
#pragma unroll
            for (int j = 0; j < 4; ++j) {
                const int col = cbase + j * 16;
                const float av = acc[i][j][r];
                float o;
                if constexpr (EPI == 0) {
                    o = av;
                } else if constexpr (EPI == 2) {
                    o = aux1[ro + col] + sigmoidf_(av + bias[col]) * __bfloat162float(aux2[ro + col]);
                } else if constexpr (EPI == 3) {
                    const float tt = av + bias[col];
                    o = tt * sigmoidf_(tt);
                } else {  // 4
                    o = av + bias[col] + aux1[ro + col];
                }
                if constexpr (__is_same(CT, float)) C[ro + col] = o;
                else                                C[ro + col] = __float2bfloat16(o);
            }
        }
    }
}

// ---------------------------------------------------------------------------
// Fused: depthwise causal conv(4) + bias + SiLU + memory injection + 16-tap
// complex FIR + per-head coupling -> eig (fp32 out) + eig_bf (bf16 operand).
// ---------------------------------------------------------------------------
#define TCH 256
#define BROWS (TCH + TAPS + 2)   // beta rows: t in [t0-18, t0+255] = 274
#define UROWS (TCH + TAPS - 1)   // u rows:    t in [t0-15, t0+255] = 271

__global__ __launch_bounds__(256) void cfc_kernel(const float* __restrict__ beta,
                                                  const float* __restrict__ mgp,
                                                  const float* __restrict__ conv_w,
                                                  const float* __restrict__ conv_b,
                                                  const float* __restrict__ log_decay,
                                                  const float* __restrict__ freq,
                                                  const float* __restrict__ coup,
                                                  float* __restrict__ eig,
                                                  __hip_bfloat16* __restrict__ eig_bf) {
    const int b = blockIdx.z, h = blockIdx.y, t0 = blockIdx.x * TCH;
    const int tid = threadIdx.x;

    __shared__ float sbeta[BROWS * 32];       // col cg: cg<16 -> real ch, else imag
    __shared__ float su[UROWS * 33];
    __shared__ float str[16 * TAPS], sti[16 * TAPS];
    __shared__ float scoup[16 * 16];
    __shared__ float scw[32 * 4], scb[32];

    auto chan = [&](int cg) { return (cg < 16) ? (h * 16 + cg) : (128 + h * 16 + cg - 16); };

    for (int idx = tid; idx < BROWS * 32; idx += 256) {
        const int r = idx >> 5, cg = idx & 31;
        const int t = t0 - (TAPS + 2) + r;
        sbeta[idx] = (t >= 0) ? beta[((size_t)b * Tn + t) * TWOK + chan(cg)] : 0.f;
    }
    for (int idx = tid; idx < UROWS * 32; idx += 256) {
        const int r = idx >> 5, cg = idx & 31;
        const int t = t0 - (TAPS - 1) + r;
        su[r * 33 + cg] = (t >= 0) ? mgp[((size_t)b * Tn + t) * TWOK + chan(cg)] : 0.f;
    }
    if (tid < 128) scw[tid] = conv_w[chan(tid >> 2) * 4 + (tid & 3)];
    else if (tid < 160) scb[tid - 128] = conv_b[chan(tid - 128)];
    scoup[tid] = coup[h * 256 + tid];
    {
        const int k = tid >> 4, d = tid & (TAPS - 1);
        const float mag = sigmoidf_(log_decay[h * 16 + k]);
        const float f = freq[h * 16 + k];
        const float p = powf(mag, (float)d);
        str[k * TAPS + d] = p * cosf(d * f);
        sti[k * TAPS + d] = p * sinf(d * f);
    }
    __syncthreads();

    for (int idx = tid; idx < UROWS * 32; idx += 256) {
        const int r = idx >> 5, cg = idx & 31;
        const int rb = r + 3;
        float v = sbeta[(rb - 3) * 32 + cg] * scw[cg * 4 + 0] +
                  sbeta[(rb - 2) * 32 + cg] * scw[cg * 4 + 1] +
                  sbeta[(rb - 1) * 32 + cg] * scw[cg * 4 + 2] +
                  sbeta[(rb - 0) * 32 + cg] * scw[cg * 4 + 3] + scb[cg];
        v = v * sigmoidf_(v);
        su[r * 33 + cg] += v;
    }
    __syncthreads();

    const int ru = tid + (TAPS - 1);
    float orr[16], oii[16];
#pragma unroll
    for (int j = 0; j < 16; ++j) { orr[j] = 0.f; oii[j] = 0.f; }
#pragma unroll 4
    for (int k = 0; k < 16; ++k) {
        float accr = 0.f, acci = 0.f;
#pragma unroll
        for (int d = 0; d < TAPS; ++d) {
            const float ur = su[(ru - d) * 33 + k];
            const float ui = su[(ru - d) * 33 + 16 + k];
            const float lr = str[k * TAPS + d], li = sti[k * TAPS + d];
            accr += lr * ur - li * ui;
            acci += lr * ui + li * ur;
        }
#pragma unroll
        for (int j = 0; j < 16; ++j) {
            orr[j] += scoup[j * 16 + k] * accr;
            oii[j] += scoup[j * 16 + k] * acci;
        }
    }
    const size_t base = ((size_t)b * Tn + t0 + tid) * TWOK + h * 16;
    float4* er = (float4*)(eig + base);
    float4* ei = (float4*)(eig + base + Kn);
#pragma unroll
    for (int q = 0; q < 4; ++q) {
        er[q] = make_float4(orr[4 * q], orr[4 * q + 1], orr[4 * q + 2], orr[4 * q + 3]);
        ei[q] = make_float4(oii[4 * q], oii[4 * q + 1], oii[4 * q + 2], oii[4 * q + 3]);
    }
#pragma unroll
    for (int j = 0; j < 16; ++j) {
        eig_bf[base + j] = __float2bfloat16(orr[j]);
        eig_bf[base + Kn + j] = __float2bfloat16(oii[j]);
    }
}

// ---------------------------------------------------------------------------
extern "C" void kernel_launch(void* const* d_in, const int* in_sizes, int n_in,
                              void* d_out, int out_size, void* d_ws, size_t ws_size,
                              hipStream_t stream) {
    const float* x          = (const float*)d_in[0];
    const float* prev_eig   = (const float*)d_in[1];
    const float* in_proj_w  = (const float*)d_in[2];
    const float* conv_w     = (const float*)d_in[3];
    const float* conv_b     = (const float*)d_in[4];
    const float* mem_gate   = (const float*)d_in[5];
    const float* mem_proj_w = (const float*)d_in[6];
    const float* log_decay  = (const float*)d_in[7];
    const float* frequency  = (const float*)d_in[8];
    const float* coupling   = (const float*)d_in[9];
    const float* out_proj_w = (const float*)d_in[10];
    const float* gate_w     = (const float*)d_in[11];
    const float* gate_b     = (const float*)d_in[12];
    const float* mlp_w1     = (const float*)d_in[13];
    const float* mlp_b1     = (const float*)d_in[14];
    const float* mlp_w2     = (const float*)d_in[15];
    const float* mlp_b2     = (const float*)d_in[16];
    const float* n1_g       = (const float*)d_in[17];
    const float* n1_b       = (const float*)d_in[18];
    const float* n2_g       = (const float*)d_in[19];
    const float* n2_b       = (const float*)d_in[20];

    float* out = (float*)d_out;                     // x2 [16384,1024]
    float* eig = out + (size_t)NROW * Dn;           // eig [16384,256] fp32

    char* wsb = (char*)d_ws;
    const size_t MB = 1 << 20;
    const bool bigws = ws_size >= 252 * MB;

    float* x1    = (float*)(wsb + 0);               // 64MB, live step8..end
    float* beta  = (float*)(wsb + 0);               //  alias, live 2-4
    float* mgp   = (float*)(wsb + 16 * MB);         //  live 3-4
    __hip_bfloat16 *h1, *eig_bf, *peig_bf, *xn_bf, *y_bf, *w1_bf, *w2_bf,
                   *gate_bf, *inpj_bf, *outpj_bf, *mempj_bf;
    if (bigws) {
        h1       = (__hip_bfloat16*)(wsb + 64 * MB);    // step 7 oproj (32MB) then step10 h1 (128MB)
        xn_bf    = (__hip_bfloat16*)(wsb + 192 * MB);   // live 1..8
        y_bf     = (__hip_bfloat16*)(wsb + 192 * MB);   //  alias (written step 9)
        w1_bf    = (__hip_bfloat16*)(wsb + 224 * MB);
        w2_bf    = (__hip_bfloat16*)(wsb + 232 * MB);
        gate_bf  = (__hip_bfloat16*)(wsb + 240 * MB);
        inpj_bf  = (__hip_bfloat16*)(wsb + 242 * MB);
        outpj_bf = (__hip_bfloat16*)(wsb + 242 * MB + 512 * 1024);
        mempj_bf = (__hip_bfloat16*)(wsb + 243 * MB);
        peig_bf  = (__hip_bfloat16*)(wsb + 244 * MB);   // live step 3 only
        eig_bf   = (__hip_bfloat16*)(wsb + 244 * MB);   //  alias (written step 4-6)
    } else {
        h1       = (__hip_bfloat16*)(wsb + 64 * MB);    // step 7 oproj (32MB) / step10 chunk h1
        eig_bf   = (__hip_bfloat16*)(wsb + 96 * MB);
        peig_bf  = (__hip_bfloat16*)(wsb + 104 * MB);
        xn_bf    = (__hip_bfloat16*)(wsb + 128 * MB);
        y_bf     = (__hip_bfloat16*)(wsb + 160 * MB);
        w1_bf    = (__hip_bfloat16*)(wsb + 192 * MB);
        w2_bf    = (__hip_bfloat16*)(wsb + 200 * MB);
        gate_bf  = (__hip_bfloat16*)(wsb + 208 * MB);
        inpj_bf  = (__hip_bfloat16*)(wsb + 210 * MB);
        outpj_bf = (__hip_bfloat16*)(wsb + 210 * MB + 512 * 1024);
        mempj_bf = (__hip_bfloat16*)(wsb + 211 * MB);
    }

    auto cvt = [&](const float* src, __hip_bfloat16* dst, int n) {
        f2bf_kernel<<<dim3((n / 4 + 255) / 256), dim3(256), 0, stream>>>(src, dst, n);
    };
    cvt(in_proj_w,  inpj_bf,  TWOK * Dn);
    cvt(mem_proj_w, mempj_bf, TWOK * TWOK);
    cvt(out_proj_w, outpj_bf, Dn * TWOK);
    cvt(gate_w,     gate_bf,  Dn * Dn);
    cvt(mlp_w1,     w1_bf,    Mmlp * Dn);
    cvt(mlp_w2,     w2_bf,    Dn * Mmlp);
    cvt(prev_eig,   peig_bf,  NROW * TWOK);

    // 1) xn = LN1(x) -> bf16
    ln_kernel<<<dim3(NROW), dim3(256), 0, stream>>>(x, n1_g, n1_b, xn_bf);
    // 2) beta = xn @ in_proj^T  [16384,256] fp32
    gemm_bf<0, float><<<dim3(2, 128), dim3(256), 0, stream>>>(
        (const ushort*)xn_bf, (const ushort*)inpj_bf, beta, NROW, TWOK, Dn, nullptr);
    // 3) mgp = sigmoid(mem_gate) * (prev_eig @ mem_proj^T)
    gemm_bf<1, float><<<dim3(2, 128), dim3(256), 0, stream>>>(
        (const ushort*)peig_bf, (const ushort*)mempj_bf, mgp, NROW, TWOK, TWOK, mem_gate);
    // 4-6) fused conv + SiLU + mem + FIR + coupling -> eig, eig_bf
    cfc_kernel<<<dim3(Tn / TCH, Hn, Bn), dim3(256), 0, stream>>>(
        beta, mgp, conv_w, conv_b, log_decay, frequency, coupling, eig, eig_bf);
    // 7) oproj = eig @ out_proj^T  [16384,1024] -> bf16 temp in h1 region
    gemmW<0, __hip_bfloat16><<<dim3(8, 64), dim3(512), 0, stream>>>(
        (const ushort*)eig_bf, (const ushort*)outpj_bf, h1, Dn, TWOK,
        nullptr, nullptr, nullptr, 2);
    // 8) x1 = x + sigmoid(xn@gate_w^T + gate_b) * oproj
    gemmW<2, float><<<dim3(8, 64), dim3(512), 0, stream>>>(
        (const ushort*)xn_bf, (const ushort*)gate_bf, x1, Dn, Dn,
        gate_b, x, h1, 2);
    // 9) y = LN2(x1) -> bf16
    ln_kernel<<<dim3(NROW), dim3(256), 0, stream>>>(x1, n2_g, n2_b, y_bf);
    // 10) MLP via gemmW
    if (bigws) {
        gemmW<3, __hip_bfloat16><<<dim3(32, 64), dim3(512), 0, stream>>>(
            (const ushort*)y_bf, (const ushort*)w1_bf, h1, Mmlp, Dn,
            mlp_b1, nullptr, nullptr, 2);
        gemmW<4, float><<<dim3(8, 64), dim3(512), 0, stream>>>(
            (const ushort*)h1, (const ushort*)w2_bf, out, Dn, Mmlp,
            mlp_b2, x1, nullptr, 2);
    } else {
        for (int ck = 0; ck < 2; ++ck) {
            const size_t roff = (size_t)ck * 8192 * Dn;
            gemmW<3, __hip_bfloat16><<<dim3(32, 32), dim3(512), 0, stream>>>(
                (const ushort*)(y_bf + roff), (const ushort*)w1_bf, h1, Mmlp, Dn,
                mlp_b1, nullptr, nullptr, 2);
            gemmW<4, float><<<dim3(8, 32), dim3(512), 0, stream>>>(
                (const ushort*)h1, (const ushort*)w2_bf, out + roff, Dn, Mmlp,
                mlp_b2, x1 + roff, nullptr, 2);
        }
    }
}

// Round 8
// 706.444 us; speedup vs baseline: 1.0355x; 1.0108x over previous
//
#include <hip/hip_runtime.h>
#include <hip/hip_bf16.h>
#include <math.h>

// Problem constants
#define Bn 4
#define Tn 4096
#define Dn 1024
#define Kn 128
#define TWOK 256
#define Hn 8
#define Mmlp 4096
#define NROW (Bn * Tn)          // 16384
#define TAPS 16                 // |lambda| <= 0.232 -> tap-16 residual ~1e-9

typedef __attribute__((ext_vector_type(8))) short bf16x8;     // 8 bf16 = 4 VGPRs
typedef __attribute__((ext_vector_type(4))) float floatx4;    // 16x16 MFMA acc

// fast sigmoid: v_exp_f32-based (__expf)
__device__ __forceinline__ float sigmoidf_(float x) { return 1.f / (1.f + __expf(-x)); }

// ---------------------------------------------------------------------------
// fp32 -> bf16 cast
// ---------------------------------------------------------------------------
__global__ __launch_bounds__(256) void f2bf_kernel(const float* __restrict__ in,
                                                   __hip_bfloat16* __restrict__ out,
                                                   int n) {
    const int i = (blockIdx.x * 256 + threadIdx.x) * 4;
    if (i >= n) return;
    const float4 v = *(const float4*)(in + i);
    out[i + 0] = __float2bfloat16(v.x);
    out[i + 1] = __float2bfloat16(v.y);
    out[i + 2] = __float2bfloat16(v.z);
    out[i + 3] = __float2bfloat16(v.w);
}

// ---------------------------------------------------------------------------
// LayerNorm (D=1024, 256 thr) -> bf16
// ---------------------------------------------------------------------------
__global__ __launch_bounds__(256) void ln_kernel(const float* __restrict__ x,
                                                 const float* __restrict__ g,
                                                 const float* __restrict__ b,
                                                 __hip_bfloat16* __restrict__ out) {
    const int row = blockIdx.x;
    const float4* xr = (const float4*)(x + (size_t)row * Dn);
    float4 v = xr[threadIdx.x];
    float s = v.x + v.y + v.z + v.w;
    float ss = v.x * v.x + v.y * v.y + v.z * v.z + v.w * v.w;
    for (int off = 32; off; off >>= 1) {
        s += __shfl_down(s, off);
        ss += __shfl_down(ss, off);
    }
    __shared__ float rs[4], rss[4];
    const int wv = threadIdx.x >> 6, ln = threadIdx.x & 63;
    if (ln == 0) { rs[wv] = s; rss[wv] = ss; }
    __syncthreads();
    s = rs[0] + rs[1] + rs[2] + rs[3];
    ss = rss[0] + rss[1] + rss[2] + rss[3];
    const float mean = s * (1.f / Dn);
    const float var = ss * (1.f / Dn) - mean * mean;
    const float inv = rsqrtf(var + 1e-5f);
    const float4 gg = ((const float4*)g)[threadIdx.x];
    const float4 bb = ((const float4*)b)[threadIdx.x];
    __hip_bfloat16* op = out + (size_t)row * Dn + threadIdx.x * 4;
    op[0] = __float2bfloat16((v.x - mean) * inv * gg.x + bb.x);
    op[1] = __float2bfloat16((v.y - mean) * inv * gg.y + bb.y);
    op[2] = __float2bfloat16((v.z - mean) * inv * gg.z + bb.z);
    op[3] = __float2bfloat16((v.w - mean) * inv * gg.w + bb.w);
}

// ---------------------------------------------------------------------------
// bf16 MFMA GEMM: C[M,N] = A[M,K] @ B[N,K]^T.  128x128 tile, BK=32, 4 waves.
// (kept for the small-N GEMMs: steps 2, 3 where N=256)
// Epilogues: 0 none | 1 C=sigmoid(bias[0])*acc
// ---------------------------------------------------------------------------
template <int EPI, typename CT>
__global__ __launch_bounds__(256, 4)
void gemm_bf(const ushort* __restrict__ A,
             const ushort* __restrict__ B,
             CT* __restrict__ C,
             int M, int N, int Kd,
             const float* __restrict__ bias) {
    __shared__ ushort As[128 * 32];   // contiguous (global_load_lds requirement)
    __shared__ ushort Bs[128 * 32];
    const int tid = threadIdx.x;
    const int nbx = gridDim.x;
    const int nblk = nbx * gridDim.y;
    int bid = blockIdx.y * nbx + blockIdx.x;
    if ((nblk & 7) == 0)
        bid = (bid & 7) * (nblk >> 3) + (bid >> 3);   // XCD strip remap
    const int m0 = (bid / nbx) * 128, n0 = (bid % nbx) * 128;
    const int wave = tid >> 6, lane = tid & 63;
    const int wm = wave >> 1, wn = wave & 1;
    const int mlane = lane & 15, quad = lane >> 4;

    floatx4 acc[4][4] = {};

    {
        const ushort* Ap = A + (size_t)m0 * Kd;
        const ushort* Bp = B + (size_t)n0 * Kd;
        for (int k0 = 0; k0 < Kd; k0 += 32) {
#pragma unroll
            for (int q = 0; q < 2; ++q) {
                const int c = q * 256 + tid;          // 16B chunk: row=c>>2, kcol=(c&3)*8
                const int row = c >> 2, kc = (c & 3) * 8;
                __builtin_amdgcn_global_load_lds(
                    (const __attribute__((address_space(1))) void*)(Ap + (size_t)row * Kd + k0 + kc),
                    (__attribute__((address_space(3))) void*)(As + c * 8), 16, 0, 0);
                __builtin_amdgcn_global_load_lds(
                    (const __attribute__((address_space(1))) void*)(Bp + (size_t)row * Kd + k0 + kc),
                    (__attribute__((address_space(3))) void*)(Bs + c * 8), 16, 0, 0);
            }
            __syncthreads();
            bf16x8 af[4], bfr[4];
#pragma unroll
            for (int t = 0; t < 4; ++t) {
                af[t]  = *(const bf16x8*)&As[(wm * 64 + t * 16 + mlane) * 32 + quad * 8];
                bfr[t] = *(const bf16x8*)&Bs[(wn * 64 + t * 16 + mlane) * 32 + quad * 8];
            }
#pragma unroll
            for (int i = 0; i < 4; ++i)
#pragma unroll
                for (int j = 0; j < 4; ++j)
                    acc[i][j] = __builtin_amdgcn_mfma_f32_16x16x32_bf16(af[i], bfr[j], acc[i][j], 0, 0, 0);
            __syncthreads();
        }
    }

    float s_pre = 0.f;
    if constexpr (EPI == 1) s_pre = sigmoidf_(bias[0]);

    const int cbase = n0 + wn * 64 + mlane;
#pragma unroll
    for (int i = 0; i < 4; ++i) {
#pragma unroll
        for (int r = 0; r < 4; ++r) {
            const int row = m0 + wm * 64 + i * 16 + quad * 4 + r;
            const size_t ro = (size_t)row * N;
#pragma unroll
            for (int j = 0; j < 4; ++j) {
                const int col = cbase + j * 16;
                const float a = acc[i][j][r];
                float o;
                if constexpr (EPI == 0) o = a;
                else                    o = s_pre * a;
                if constexpr (__is_same(CT, float)) C[ro + col] = o;
                else                                C[ro + col] = __float2bfloat16(o);
            }
        }
    }
}

// ---------------------------------------------------------------------------
// gemmP (v5): 256x256-tile bf16 GEMM, software-pipelined 1-barrier schedule.
// C[M,N] = A[M,K] @ B[N,K]^T.  BK=32, 8 waves (2Mx4N, 128x64 per wave),
// 4-deep LDS ring (4 x 32KB = 128KB), two fragment register sets.
//
// Why (r7 post-mortem): 4 structures all pinned at ~31% MfmaUtil with NO
// pipe saturated (MFMA 31, VALU 34, LDS ~43) -> latency-bound at sync
// points.  v5 makes every wait land on OLD work:
//   step t: vmcnt(4)            // stage(t) landed -- issued 2 steps
//                               // (~2500cy) earlier >> 900cy HBM latency
//           s_barrier           // the ONLY barrier per step
//           rd(t): 12 ds_read_b128 -> set[t&1]   (buf[t&3])
//           stage(t+2): 4 global_load_lds -> buf[(t+2)&3]
//           MFMA(t-1): 32 mfma on set[(t-1)&1]   (setprio-wrapped)
// MFMAs consume step-OLD registers, so the LDS burst of step t overlaps
// the MFMAs of step t-1 (hipcc inserts precise counted lgkmcnt from the
// register dataflow -- r2/r3 proved the no-drain path numerically safe).
// Hazards: RAW rd(t) vs stage(t): vmcnt(4)+barrier (vmcnt(0) at tail).
// WAR stage(t+2) vs rd(t-2) of buf[(t+2)&3]: every wave's MFMA(t-2) at
// step t-1 consumed all 12 regs -> rd(t-2) drained before its last MFMA
// issued -> barrier@t -> my stage(t+2) after.  All in-order queues.
// LDS layout/swizzle/staging = gemmW's harness-proven 0-conflict pair
// (write-side pre-swizzled global source, read-side quad^((mlane>>1)&3)).
// ~244 regs -> 1 block/CU (same as m201's verified 62% kernel).
// Requirements: M,N % 256 == 0, K % 64 == 0 (NT even), K >= 128.
// Epilogues: 0 C=acc | 2 C=aux1+sig(acc+bias)*aux2 | 3 C=silu(acc+bias)
//            | 4 C=acc+bias+aux1
// ---------------------------------------------------------------------------
template <int EPI, typename CT>
__global__ __launch_bounds__(512, 2)
void gemmP(const ushort* __restrict__ A, const ushort* __restrict__ B,
           CT* __restrict__ C, int N, int Kd,
           const float* __restrict__ bias, const float* __restrict__ aux1,
           const __hip_bfloat16* __restrict__ aux2, int cg) {
    __shared__ ushort As[4 * 8192];   // 64 KiB: 4 ring slots of [256][32]
    __shared__ ushort Bs[4 * 8192];   // 64 KiB
    const int tid = threadIdx.x;
    const int nbx = gridDim.x;
    const int nblk = nbx * gridDim.y;
    const int nrows = nblk / nbx;
    int bid = blockIdx.y * nbx + blockIdx.x;
    int mt, ntile;
    if ((nblk & 7) == 0 && cg > 0 && nbx % cg == 0 && nrows % (8 / cg) == 0) {
        const int xcd = bid & 7, i = bid >> 3;
        const int cPerG = nbx / cg;
        const int rPerG = nrows / (8 / cg);
        const int rg = xcd / cg, cgi = xcd % cg;
        mt = rg * rPerG + i / cPerG;
        ntile = cgi * cPerG + i % cPerG;
    } else {
        mt = bid / nbx; ntile = bid % nbx;
    }
    const int m0 = mt * 256, n0 = ntile * 256;
    const int wave = tid >> 6, lane = tid & 63;
    const int wm = wave >> 2, wn = wave & 3;          // 2M x 4N wave grid
    const int mlane = lane & 15, quad = lane >> 4;
    const int oswz = (quad ^ ((mlane >> 1) & 3)) * 8; // swizzled read octet
    const int NT = Kd >> 5;                           // K-tiles of 32 (even)

    // staging map (gemmW-proven): chunk c covers row c>>2, octet (c&3)^((row>>1)&3)
    const int cA0 = tid, cA1 = 512 + tid;             // two A chunks / thread
    const int rA0 = cA0 >> 2, rA1 = cA1 >> 2;
    const ushort* aSrc0 = A + (size_t)(m0 + rA0) * Kd + (((cA0 & 3) ^ ((rA0 >> 1) & 3)) << 3);
    const ushort* aSrc1 = A + (size_t)(m0 + rA1) * Kd + (((cA1 & 3) ^ ((rA1 >> 1) & 3)) << 3);
    const ushort* bSrc0 = B + (size_t)(n0 + rA0) * Kd + (((cA0 & 3) ^ ((rA0 >> 1) & 3)) << 3);
    const ushort* bSrc1 = B + (size_t)(n0 + rA1) * Kd + (((cA1 & 3) ^ ((rA1 >> 1) & 3)) << 3);

    auto stage = [&](int t) {   // 4 x global_load_lds (A 2, B 2) -> ring slot t&3
        const int s = (t & 3) * 8192;
        const int kk = t << 5;
        __builtin_amdgcn_global_load_lds(
            (const __attribute__((address_space(1))) void*)(aSrc0 + kk),
            (__attribute__((address_space(3))) void*)(As + s + cA0 * 8), 16, 0, 0);
        __builtin_amdgcn_global_load_lds(
            (const __attribute__((address_space(1))) void*)(aSrc1 + kk),
            (__attribute__((address_space(3))) void*)(As + s + cA1 * 8), 16, 0, 0);
        __builtin_amdgcn_global_load_lds(
            (const __attribute__((address_space(1))) void*)(bSrc0 + kk),
            (__attribute__((address_space(3))) void*)(Bs + s + cA0 * 8), 16, 0, 0);
        __builtin_amdgcn_global_load_lds(
            (const __attribute__((address_space(1))) void*)(bSrc1 + kk),
            (__attribute__((address_space(3))) void*)(Bs + s + cA1 * 8), 16, 0, 0);
    };

    floatx4 acc[8][4] = {};
    bf16x8 fa0[8], fb0[4], fa1[8], fb1[4];            // two fragment sets

    const int arow = wm * 128 + mlane;                // A frag row base
    const int brow = wn * 64 + mlane;

#define RDSET(FA, FB, T)                                                     \
    {                                                                        \
        const ushort* lA = As + ((T) & 3) * 8192;                            \
        const ushort* lB = Bs + ((T) & 3) * 8192;                            \
        _Pragma("unroll")                                                    \
        for (int f_ = 0; f_ < 8; ++f_)                                       \
            FA[f_] = *(const bf16x8*)(lA + (arow + f_ * 16) * 32 + oswz);    \
        _Pragma("unroll")                                                    \
        for (int g_ = 0; g_ < 4; ++g_)                                       \
            FB[g_] = *(const bf16x8*)(lB + (brow + g_ * 16) * 32 + oswz);    \
    }

#define MMSET(FA, FB)                                                        \
    __builtin_amdgcn_s_setprio(1);                                           \
    _Pragma("unroll")                                                        \
    for (int f_ = 0; f_ < 8; ++f_) {                                         \
        _Pragma("unroll")                                                    \
        for (int g_ = 0; g_ < 4; ++g_) {                                     \
            acc[f_][g_] = __builtin_amdgcn_mfma_f32_16x16x32_bf16(           \
                FA[f_], FB[g_], acc[f_][g_], 0, 0, 0);                       \
        }                                                                    \
    }                                                                        \
    __builtin_amdgcn_s_setprio(0);

#define VMW(T)                                                               \
    if ((T) + 1 < NT) { asm volatile("s_waitcnt vmcnt(4)" ::: "memory"); }   \
    else              { asm volatile("s_waitcnt vmcnt(0)" ::: "memory"); }

    // prologue: stage tiles 0,1 (8 loads in flight)
    stage(0); stage(1);
    // t = 0: no MFMA yet
    VMW(0)
    __builtin_amdgcn_s_barrier();
    RDSET(fa0, fb0, 0)
    if (2 < NT) stage(2);
    // t = 1
    VMW(1)
    __builtin_amdgcn_s_barrier();
    RDSET(fa1, fb1, 1)
    if (3 < NT) stage(3);
    MMSET(fa0, fb0)
    // steady state, pair-unrolled for static register-set indices
    for (int u = 1; u < (NT >> 1); ++u) {
        const int te = 2 * u;
        VMW(te)
        __builtin_amdgcn_s_barrier();
        RDSET(fa0, fb0, te)
        if (te + 2 < NT) stage(te + 2);
        MMSET(fa1, fb1)
        const int to = te + 1;
        VMW(to)
        __builtin_amdgcn_s_barrier();
        RDSET(fa1, fb1, to)
        if (to + 2 < NT) stage(to + 2);
        MMSET(fa0, fb0)
    }
    // epilogue MFMA: tile NT-1 (odd since NT even) lives in set 1
    MMSET(fa1, fb1)
#undef RDSET
#undef MMSET
#undef VMW

    // epilogue: 16x16 C/D layout (harness-verified): col=mlane, row=quad*4+r
    const int cbase = n0 + wn * 64 + mlane;
#pragma unroll
    for (int f = 0; f < 8; ++f) {
#pragma unroll
        for (int r = 0; r < 4; ++r) {
            const int row = m0 + wm * 128 + f * 16 + quad * 4 + r;
            const size_t ro = (size_t)row * N;
#pragma unroll
            for (int g = 0; g < 4; ++g) {
                const int col = cbase + g * 16;
                const float av = acc[f][g][r];
                float o;
                if constexpr (EPI == 0) {
                    o = av;
                } else if constexpr (EPI == 2) {
                    o = aux1[ro + col] + sigmoidf_(av + bias[col]) * __bfloat162float(aux2[ro + col]);
                } else if constexpr (EPI == 3) {
                    const float tt = av + bias[col];
                    o = tt * sigmoidf_(tt);
                } else {  // 4
                    o = av + bias[col] + aux1[ro + col];
                }
                if constexpr (__is_same(CT, float)) C[ro + col] = o;
                else                                C[ro + col] = __float2bfloat16(o);
            }
        }
    }
}

// ---------------------------------------------------------------------------
// Fused: depthwise causal conv(4) + bias + SiLU + memory injection + 16-tap
// complex FIR + per-head coupling -> eig (fp32 out) + eig_bf (bf16 operand).
// ---------------------------------------------------------------------------
#define TCH 256
#define BROWS (TCH + TAPS + 2)   // beta rows: t in [t0-18, t0+255] = 274
#define UROWS (TCH + TAPS - 1)   // u rows:    t in [t0-15, t0+255] = 271

__global__ __launch_bounds__(256) void cfc_kernel(const float* __restrict__ beta,
                                                  const float* __restrict__ mgp,
                                                  const float* __restrict__ conv_w,
                                                  const float* __restrict__ conv_b,
                                                  const float* __restrict__ log_decay,
                                                  const float* __restrict__ freq,
                                                  const float* __restrict__ coup,
                                                  float* __restrict__ eig,
                                                  __hip_bfloat16* __restrict__ eig_bf) {
    const int b = blockIdx.z, h = blockIdx.y, t0 = blockIdx.x * TCH;
    const int tid = threadIdx.x;

    __shared__ float sbeta[BROWS * 32];       // col cg: cg<16 -> real ch, else imag
    __shared__ float su[UROWS * 33];
    __shared__ float str[16 * TAPS], sti[16 * TAPS];
    __shared__ float scoup[16 * 16];
    __shared__ float scw[32 * 4], scb[32];

    auto chan = [&](int cg) { return (cg < 16) ? (h * 16 + cg) : (128 + h * 16 + cg - 16); };

    for (int idx = tid; idx < BROWS * 32; idx += 256) {
        const int r = idx >> 5, cg = idx & 31;
        const int t = t0 - (TAPS + 2) + r;
        sbeta[idx] = (t >= 0) ? beta[((size_t)b * Tn + t) * TWOK + chan(cg)] : 0.f;
    }
    for (int idx = tid; idx < UROWS * 32; idx += 256) {
        const int r = idx >> 5, cg = idx & 31;
        const int t = t0 - (TAPS - 1) + r;
        su[r * 33 + cg] = (t >= 0) ? mgp[((size_t)b * Tn + t) * TWOK + chan(cg)] : 0.f;
    }
    if (tid < 128) scw[tid] = conv_w[chan(tid >> 2) * 4 + (tid & 3)];
    else if (tid < 160) scb[tid - 128] = conv_b[chan(tid - 128)];
    scoup[tid] = coup[h * 256 + tid];
    {
        const int k = tid >> 4, d = tid & (TAPS - 1);
        const float mag = sigmoidf_(log_decay[h * 16 + k]);
        const float f = freq[h * 16 + k];
        const float p = powf(mag, (float)d);
        str[k * TAPS + d] = p * cosf(d * f);
        sti[k * TAPS + d] = p * sinf(d * f);
    }
    __syncthreads();

    for (int idx = tid; idx < UROWS * 32; idx += 256) {
        const int r = idx >> 5, cg = idx & 31;
        const int rb = r + 3;
        float v = sbeta[(rb - 3) * 32 + cg] * scw[cg * 4 + 0] +
                  sbeta[(rb - 2) * 32 + cg] * scw[cg * 4 + 1] +
                  sbeta[(rb - 1) * 32 + cg] * scw[cg * 4 + 2] +
                  sbeta[(rb - 0) * 32 + cg] * scw[cg * 4 + 3] + scb[cg];
        v = v * sigmoidf_(v);
        su[r * 33 + cg] += v;
    }
    __syncthreads();

    const int ru = tid + (TAPS - 1);
    float orr[16], oii[16];
#pragma unroll
    for (int j = 0; j < 16; ++j) { orr[j] = 0.f; oii[j] = 0.f; }
#pragma unroll 4
    for (int k = 0; k < 16; ++k) {
        float accr = 0.f, acci = 0.f;
#pragma unroll
        for (int d = 0; d < TAPS; ++d) {
            const float ur = su[(ru - d) * 33 + k];
            const float ui = su[(ru - d) * 33 + 16 + k];
            const float lr = str[k * TAPS + d], li = sti[k * TAPS + d];
            accr += lr * ur - li * ui;
            acci += lr * ui + li * ur;
        }
#pragma unroll
        for (int j = 0; j < 16; ++j) {
            orr[j] += scoup[j * 16 + k] * accr;
            oii[j] += scoup[j * 16 + k] * acci;
        }
    }
    const size_t base = ((size_t)b * Tn + t0 + tid) * TWOK + h * 16;
    float4* er = (float4*)(eig + base);
    float4* ei = (float4*)(eig + base + Kn);
#pragma unroll
    for (int q = 0; q < 4; ++q) {
        er[q] = make_float4(orr[4 * q], orr[4 * q + 1], orr[4 * q + 2], orr[4 * q + 3]);
        ei[q] = make_float4(oii[4 * q], oii[4 * q + 1], oii[4 * q + 2], oii[4 * q + 3]);
    }
#pragma unroll
    for (int j = 0; j < 16; ++j) {
        eig_bf[base + j] = __float2bfloat16(orr[j]);
        eig_bf[base + Kn + j] = __float2bfloat16(oii[j]);
    }
}

// ---------------------------------------------------------------------------
extern "C" void kernel_launch(void* const* d_in, const int* in_sizes, int n_in,
                              void* d_out, int out_size, void* d_ws, size_t ws_size,
                              hipStream_t stream) {
    const float* x          = (const float*)d_in[0];
    const float* prev_eig   = (const float*)d_in[1];
    const float* in_proj_w  = (const float*)d_in[2];
    const float* conv_w     = (const float*)d_in[3];
    const float* conv_b     = (const float*)d_in[4];
    const float* mem_gate   = (const float*)d_in[5];
    const float* mem_proj_w = (const float*)d_in[6];
    const float* log_decay  = (const float*)d_in[7];
    const float* frequency  = (const float*)d_in[8];
    const float* coupling   = (const float*)d_in[9];
    const float* out_proj_w = (const float*)d_in[10];
    const float* gate_w     = (const float*)d_in[11];
    const float* gate_b     = (const float*)d_in[12];
    const float* mlp_w1     = (const float*)d_in[13];
    const float* mlp_b1     = (const float*)d_in[14];
    const float* mlp_w2     = (const float*)d_in[15];
    const float* mlp_b2     = (const float*)d_in[16];
    const float* n1_g       = (const float*)d_in[17];
    const float* n1_b       = (const float*)d_in[18];
    const float* n2_g       = (const float*)d_in[19];
    const float* n2_b       = (const float*)d_in[20];

    float* out = (float*)d_out;                     // x2 [16384,1024]
    float* eig = out + (size_t)NROW * Dn;           // eig [16384,256] fp32

    char* wsb = (char*)d_ws;
    const size_t MB = 1 << 20;
    const bool bigws = ws_size >= 252 * MB;

    float* x1    = (float*)(wsb + 0);               // 64MB, live step8..end
    float* beta  = (float*)(wsb + 0);               //  alias, live 2-4
    float* mgp   = (float*)(wsb + 16 * MB);         //  live 3-4
    __hip_bfloat16 *h1, *eig_bf, *peig_bf, *xn_bf, *y_bf, *w1_bf, *w2_bf,
                   *gate_bf, *inpj_bf, *outpj_bf, *mempj_bf;
    if (bigws) {
        h1       = (__hip_bfloat16*)(wsb + 64 * MB);    // step 7 oproj (32MB) then step10 h1 (128MB)
        xn_bf    = (__hip_bfloat16*)(wsb + 192 * MB);   // live 1..8
        y_bf     = (__hip_bfloat16*)(wsb + 192 * MB);   //  alias (written step 9)
        w1_bf    = (__hip_bfloat16*)(wsb + 224 * MB);
        w2_bf    = (__hip_bfloat16*)(wsb + 232 * MB);
        gate_bf  = (__hip_bfloat16*)(wsb + 240 * MB);
        inpj_bf  = (__hip_bfloat16*)(wsb + 242 * MB);
        outpj_bf = (__hip_bfloat16*)(wsb + 242 * MB + 512 * 1024);
        mempj_bf = (__hip_bfloat16*)(wsb + 243 * MB);
        peig_bf  = (__hip_bfloat16*)(wsb + 244 * MB);   // live step 3 only
        eig_bf   = (__hip_bfloat16*)(wsb + 244 * MB);   //  alias (written step 4-6)
    } else {
        h1       = (__hip_bfloat16*)(wsb + 64 * MB);    // step 7 oproj (32MB) / step10 chunk h1
        eig_bf   = (__hip_bfloat16*)(wsb + 96 * MB);
        peig_bf  = (__hip_bfloat16*)(wsb + 104 * MB);
        xn_bf    = (__hip_bfloat16*)(wsb + 128 * MB);
        y_bf     = (__hip_bfloat16*)(wsb + 160 * MB);
        w1_bf    = (__hip_bfloat16*)(wsb + 192 * MB);
        w2_bf    = (__hip_bfloat16*)(wsb + 200 * MB);
        gate_bf  = (__hip_bfloat16*)(wsb + 208 * MB);
        inpj_bf  = (__hip_bfloat16*)(wsb + 210 * MB);
        outpj_bf = (__hip_bfloat16*)(wsb + 210 * MB + 512 * 1024);
        mempj_bf = (__hip_bfloat16*)(wsb + 211 * MB);
    }

    auto cvt = [&](const float* src, __hip_bfloat16* dst, int n) {
        f2bf_kernel<<<dim3((n / 4 + 255) / 256), dim3(256), 0, stream>>>(src, dst, n);
    };
    cvt(in_proj_w,  inpj_bf,  TWOK * Dn);
    cvt(mem_proj_w, mempj_bf, TWOK * TWOK);
    cvt(out_proj_w, outpj_bf, Dn * TWOK);
    cvt(gate_w,     gate_bf,  Dn * Dn);
    cvt(mlp_w1,     w1_bf,    Mmlp * Dn);
    cvt(mlp_w2,     w2_bf,    Dn * Mmlp);
    cvt(prev_eig,   peig_bf,  NROW * TWOK);

    // 1) xn = LN1(x) -> bf16
    ln_kernel<<<dim3(NROW), dim3(256), 0, stream>>>(x, n1_g, n1_b, xn_bf);
    // 2) beta = xn @ in_proj^T  [16384,256] fp32
    gemm_bf<0, float><<<dim3(2, 128), dim3(256), 0, stream>>>(
        (const ushort*)xn_bf, (const ushort*)inpj_bf, beta, NROW, TWOK, Dn, nullptr);
    // 3) mgp = sigmoid(mem_gate) * (prev_eig @ mem_proj^T)
    gemm_bf<1, float><<<dim3(2, 128), dim3(256), 0, stream>>>(
        (const ushort*)peig_bf, (const ushort*)mempj_bf, mgp, NROW, TWOK, TWOK, mem_gate);
    // 4-6) fused conv + SiLU + mem + FIR + coupling -> eig, eig_bf
    cfc_kernel<<<dim3(Tn / TCH, Hn, Bn), dim3(256), 0, stream>>>(
        beta, mgp, conv_w, conv_b, log_decay, frequency, coupling, eig, eig_bf);
    // 7) oproj = eig @ out_proj^T  [16384,1024] -> bf16 temp in h1 region
    gemmP<0, __hip_bfloat16><<<dim3(4, 64), dim3(512), 0, stream>>>(
        (const ushort*)eig_bf, (const ushort*)outpj_bf, h1, Dn, TWOK,
        nullptr, nullptr, nullptr, 2);
    // 8) x1 = x + sigmoid(xn@gate_w^T + gate_b) * oproj
    gemmP<2, float><<<dim3(4, 64), dim3(512), 0, stream>>>(
        (const ushort*)xn_bf, (const ushort*)gate_bf, x1, Dn, Dn,
        gate_b, x, h1, 2);
    // 9) y = LN2(x1) -> bf16
    ln_kernel<<<dim3(NROW), dim3(256), 0, stream>>>(x1, n2_g, n2_b, y_bf);
    // 10) MLP via gemmP
    if (bigws) {
        gemmP<3, __hip_bfloat16><<<dim3(16, 64), dim3(512), 0, stream>>>(
            (const ushort*)y_bf, (const ushort*)w1_bf, h1, Mmlp, Dn,
            mlp_b1, nullptr, nullptr, 2);
        gemmP<4, float><<<dim3(4, 64), dim3(512), 0, stream>>>(
            (const ushort*)h1, (const ushort*)w2_bf, out, Dn, Mmlp,
            mlp_b2, x1, nullptr, 2);
    } else {
        for (int ck = 0; ck < 2; ++ck) {
            const size_t roff = (size_t)ck * 8192 * Dn;
            gemmP<3, __hip_bfloat16><<<dim3(16, 32), dim3(512), 0, stream>>>(
                (const ushort*)(y_bf + roff), (const ushort*)w1_bf, h1, Mmlp, Dn,
                mlp_b1, nullptr, nullptr, 2);
            gemmP<4, float><<<dim3(8, 32), dim3(512), 0, stream>>>(
                (const ushort*)h1, (const ushort*)w2_bf, out + roff, Dn, Mmlp,
                mlp_b2, x1 + roff, nullptr, 2);
        }
    }
}

// Round 9
// 658.834 us; speedup vs baseline: 1.1103x; 1.0723x over previous
//
#include <hip/hip_runtime.h>
#include <hip/hip_bf16.h>
#include <math.h>

// Problem constants
#define Bn 4
#define Tn 4096
#define Dn 1024
#define Kn 128
#define TWOK 256
#define Hn 8
#define Mmlp 4096
#define NROW (Bn * Tn)          // 16384
#define TAPS 16                 // |lambda| <= 0.232 -> tap-16 residual ~1e-9

typedef __attribute__((ext_vector_type(8))) short bf16x8;     // 8 bf16 = 4 VGPRs
typedef __attribute__((ext_vector_type(4))) float floatx4;    // 16x16 MFMA acc

// fast sigmoid: v_exp_f32-based (__expf)
__device__ __forceinline__ float sigmoidf_(float x) { return 1.f / (1.f + __expf(-x)); }

// ---------------------------------------------------------------------------
// Fused fp32 -> bf16 cast over the 7 weight/activation tensors (1 launch
// replaces 7; launch overhead ~10us each dominated actual BW time ~15us).
// Segment boundaries are compile-time (all sizes are problem constants).
// Chunks are float4 (4 elems).  Prefix sums (in chunks):
//   inpj 65536 | mempj 16384 | outpj 65536 | gate 262144
//   w1 1048576 | w2 1048576 | peig 1048576   -> total 3555328
// ---------------------------------------------------------------------------
#define MC_TOT 3555328
__global__ __launch_bounds__(256) void multicast_kernel(
    const float* __restrict__ s0, __hip_bfloat16* __restrict__ d0,
    const float* __restrict__ s1, __hip_bfloat16* __restrict__ d1,
    const float* __restrict__ s2, __hip_bfloat16* __restrict__ d2,
    const float* __restrict__ s3, __hip_bfloat16* __restrict__ d3,
    const float* __restrict__ s4, __hip_bfloat16* __restrict__ d4,
    const float* __restrict__ s5, __hip_bfloat16* __restrict__ d5,
    const float* __restrict__ s6, __hip_bfloat16* __restrict__ d6) {
    for (int i = blockIdx.x * 256 + threadIdx.x; i < MC_TOT; i += gridDim.x * 256) {
        const float* s; __hip_bfloat16* d; int off;
        if      (i <   65536) { s = s0; d = d0; off = i; }
        else if (i <   81920) { s = s1; d = d1; off = i -   65536; }
        else if (i <  147456) { s = s2; d = d2; off = i -   81920; }
        else if (i <  409600) { s = s3; d = d3; off = i -  147456; }
        else if (i < 1458176) { s = s4; d = d4; off = i -  409600; }
        else if (i < 2506752) { s = s5; d = d5; off = i - 1458176; }
        else                  { s = s6; d = d6; off = i - 2506752; }
        const float4 v = ((const float4*)s)[off];
        d[off * 4 + 0] = __float2bfloat16(v.x);
        d[off * 4 + 1] = __float2bfloat16(v.y);
        d[off * 4 + 2] = __float2bfloat16(v.z);
        d[off * 4 + 3] = __float2bfloat16(v.w);
    }
}

// ---------------------------------------------------------------------------
// LayerNorm (D=1024, 256 thr) -> bf16
// ---------------------------------------------------------------------------
__global__ __launch_bounds__(256) void ln_kernel(const float* __restrict__ x,
                                                 const float* __restrict__ g,
                                                 const float* __restrict__ b,
                                                 __hip_bfloat16* __restrict__ out) {
    const int row = blockIdx.x;
    const float4* xr = (const float4*)(x + (size_t)row * Dn);
    float4 v = xr[threadIdx.x];
    float s = v.x + v.y + v.z + v.w;
    float ss = v.x * v.x + v.y * v.y + v.z * v.z + v.w * v.w;
    for (int off = 32; off; off >>= 1) {
        s += __shfl_down(s, off);
        ss += __shfl_down(ss, off);
    }
    __shared__ float rs[4], rss[4];
    const int wv = threadIdx.x >> 6, ln = threadIdx.x & 63;
    if (ln == 0) { rs[wv] = s; rss[wv] = ss; }
    __syncthreads();
    s = rs[0] + rs[1] + rs[2] + rs[3];
    ss = rss[0] + rss[1] + rss[2] + rss[3];
    const float mean = s * (1.f / Dn);
    const float var = ss * (1.f / Dn) - mean * mean;
    const float inv = rsqrtf(var + 1e-5f);
    const float4 gg = ((const float4*)g)[threadIdx.x];
    const float4 bb = ((const float4*)b)[threadIdx.x];
    __hip_bfloat16* op = out + (size_t)row * Dn + threadIdx.x * 4;
    op[0] = __float2bfloat16((v.x - mean) * inv * gg.x + bb.x);
    op[1] = __float2bfloat16((v.y - mean) * inv * gg.y + bb.y);
    op[2] = __float2bfloat16((v.z - mean) * inv * gg.z + bb.z);
    op[3] = __float2bfloat16((v.w - mean) * inv * gg.w + bb.w);
}

// ---------------------------------------------------------------------------
// bf16 MFMA GEMM: C[M,N] = A[M,K] @ B[N,K]^T.  128x128 tile, BK=32, 4 waves.
// (kept for the small-N GEMMs: steps 2, 3 where N=256)
// Epilogues: 0 none | 1 C=sigmoid(bias[0])*acc
// ---------------------------------------------------------------------------
template <int EPI, typename CT>
__global__ __launch_bounds__(256, 4)
void gemm_bf(const ushort* __restrict__ A,
             const ushort* __restrict__ B,
             CT* __restrict__ C,
             int M, int N, int Kd,
             const float* __restrict__ bias) {
    __shared__ ushort As[128 * 32];   // contiguous (global_load_lds requirement)
    __shared__ ushort Bs[128 * 32];
    const int tid = threadIdx.x;
    const int nbx = gridDim.x;
    const int nblk = nbx * gridDim.y;
    int bid = blockIdx.y * nbx + blockIdx.x;
    if ((nblk & 7) == 0)
        bid = (bid & 7) * (nblk >> 3) + (bid >> 3);   // XCD strip remap
    const int m0 = (bid / nbx) * 128, n0 = (bid % nbx) * 128;
    const int wave = tid >> 6, lane = tid & 63;
    const int wm = wave >> 1, wn = wave & 1;
    const int mlane = lane & 15, quad = lane >> 4;

    floatx4 acc[4][4] = {};

    {
        const ushort* Ap = A + (size_t)m0 * Kd;
        const ushort* Bp = B + (size_t)n0 * Kd;
        for (int k0 = 0; k0 < Kd; k0 += 32) {
#pragma unroll
            for (int q = 0; q < 2; ++q) {
                const int c = q * 256 + tid;          // 16B chunk: row=c>>2, kcol=(c&3)*8
                const int row = c >> 2, kc = (c & 3) * 8;
                __builtin_amdgcn_global_load_lds(
                    (const __attribute__((address_space(1))) void*)(Ap + (size_t)row * Kd + k0 + kc),
                    (__attribute__((address_space(3))) void*)(As + c * 8), 16, 0, 0);
                __builtin_amdgcn_global_load_lds(
                    (const __attribute__((address_space(1))) void*)(Bp + (size_t)row * Kd + k0 + kc),
                    (__attribute__((address_space(3))) void*)(Bs + c * 8), 16, 0, 0);
            }
            __syncthreads();
            bf16x8 af[4], bfr[4];
#pragma unroll
            for (int t = 0; t < 4; ++t) {
                af[t]  = *(const bf16x8*)&As[(wm * 64 + t * 16 + mlane) * 32 + quad * 8];
                bfr[t] = *(const bf16x8*)&Bs[(wn * 64 + t * 16 + mlane) * 32 + quad * 8];
            }
#pragma unroll
            for (int i = 0; i < 4; ++i)
#pragma unroll
                for (int j = 0; j < 4; ++j)
                    acc[i][j] = __builtin_amdgcn_mfma_f32_16x16x32_bf16(af[i], bfr[j], acc[i][j], 0, 0, 0);
            __syncthreads();
        }
    }

    float s_pre = 0.f;
    if constexpr (EPI == 1) s_pre = sigmoidf_(bias[0]);

    const int cbase = n0 + wn * 64 + mlane;
#pragma unroll
    for (int i = 0; i < 4; ++i) {
#pragma unroll
        for (int r = 0; r < 4; ++r) {
            const int row = m0 + wm * 64 + i * 16 + quad * 4 + r;
            const size_t ro = (size_t)row * N;
#pragma unroll
            for (int j = 0; j < 4; ++j) {
                const int col = cbase + j * 16;
                const float a = acc[i][j][r];
                float o;
                if constexpr (EPI == 0) o = a;
                else                    o = s_pre * a;
                if constexpr (__is_same(CT, float)) C[ro + col] = o;
                else                                C[ro + col] = __float2bfloat16(o);
            }
        }
    }
}

// ---------------------------------------------------------------------------
// gemmP (v5): 256x256-tile bf16 GEMM, software-pipelined 1-barrier schedule.
// C[M,N] = A[M,K] @ B[N,K]^T.  BK=32, 8 waves (2Mx4N, 128x64 per wave),
// 4-deep LDS ring (4 x 32KB = 128KB), two fragment register sets.
// (unchanged from r8 -- best measured GEMM: MfmaUtil 34%, 0 conflicts)
// Requirements: M,N % 256 == 0, K % 64 == 0 (NT even), K >= 128.
// Epilogues: 0 C=acc | 2 C=aux1+sig(acc+bias)*aux2 | 3 C=silu(acc+bias)
//            | 4 C=acc+bias+aux1
// cg: XCD remap column-groups.  For N=1024 grids (4 ntiles), cg=1 gives
// each XCD 8 m-rows x all 4 ntiles -> the 4 blocks sharing an A-panel are
// co-resident on ONE XCD (1 HBM fetch + 3 L2 hits); cg=2 split them across
// 2 XCDs (2x A HBM traffic) -- r8 FETCH 180MB on MLP2.
// ---------------------------------------------------------------------------
template <int EPI, typename CT>
__global__ __launch_bounds__(512, 2)
void gemmP(const ushort* __restrict__ A, const ushort* __restrict__ B,
           CT* __restrict__ C, int N, int Kd,
           const float* __restrict__ bias, const float* __restrict__ aux1,
           const __hip_bfloat16* __restrict__ aux2, int cg) {
    __shared__ ushort As[4 * 8192];   // 64 KiB: 4 ring slots of [256][32]
    __shared__ ushort Bs[4 * 8192];   // 64 KiB
    const int tid = threadIdx.x;
    const int nbx = gridDim.x;
    const int nblk = nbx * gridDim.y;
    const int nrows = nblk / nbx;
    int bid = blockIdx.y * nbx + blockIdx.x;
    int mt, ntile;
    if ((nblk & 7) == 0 && cg > 0 && nbx % cg == 0 && nrows % (8 / cg) == 0) {
        const int xcd = bid & 7, i = bid >> 3;
        const int cPerG = nbx / cg;
        const int rPerG = nrows / (8 / cg);
        const int rg = xcd / cg, cgi = xcd % cg;
        mt = rg * rPerG + i / cPerG;
        ntile = cgi * cPerG + i % cPerG;
    } else {
        mt = bid / nbx; ntile = bid % nbx;
    }
    const int m0 = mt * 256, n0 = ntile * 256;
    const int wave = tid >> 6, lane = tid & 63;
    const int wm = wave >> 2, wn = wave & 3;          // 2M x 4N wave grid
    const int mlane = lane & 15, quad = lane >> 4;
    const int oswz = (quad ^ ((mlane >> 1) & 3)) * 8; // swizzled read octet
    const int NT = Kd >> 5;                           // K-tiles of 32 (even)

    // staging map (gemmW-proven): chunk c covers row c>>2, octet (c&3)^((row>>1)&3)
    const int cA0 = tid, cA1 = 512 + tid;             // two A chunks / thread
    const int rA0 = cA0 >> 2, rA1 = cA1 >> 2;
    const ushort* aSrc0 = A + (size_t)(m0 + rA0) * Kd + (((cA0 & 3) ^ ((rA0 >> 1) & 3)) << 3);
    const ushort* aSrc1 = A + (size_t)(m0 + rA1) * Kd + (((cA1 & 3) ^ ((rA1 >> 1) & 3)) << 3);
    const ushort* bSrc0 = B + (size_t)(n0 + rA0) * Kd + (((cA0 & 3) ^ ((rA0 >> 1) & 3)) << 3);
    const ushort* bSrc1 = B + (size_t)(n0 + rA1) * Kd + (((cA1 & 3) ^ ((rA1 >> 1) & 3)) << 3);

    auto stage = [&](int t) {   // 4 x global_load_lds (A 2, B 2) -> ring slot t&3
        const int s = (t & 3) * 8192;
        const int kk = t << 5;
        __builtin_amdgcn_global_load_lds(
            (const __attribute__((address_space(1))) void*)(aSrc0 + kk),
            (__attribute__((address_space(3))) void*)(As + s + cA0 * 8), 16, 0, 0);
        __builtin_amdgcn_global_load_lds(
            (const __attribute__((address_space(1))) void*)(aSrc1 + kk),
            (__attribute__((address_space(3))) void*)(As + s + cA1 * 8), 16, 0, 0);
        __builtin_amdgcn_global_load_lds(
            (const __attribute__((address_space(1))) void*)(bSrc0 + kk),
            (__attribute__((address_space(3))) void*)(Bs + s + cA0 * 8), 16, 0, 0);
        __builtin_amdgcn_global_load_lds(
            (const __attribute__((address_space(1))) void*)(bSrc1 + kk),
            (__attribute__((address_space(3))) void*)(Bs + s + cA1 * 8), 16, 0, 0);
    };

    floatx4 acc[8][4] = {};
    bf16x8 fa0[8], fb0[4], fa1[8], fb1[4];            // two fragment sets

    const int arow = wm * 128 + mlane;                // A frag row base
    const int brow = wn * 64 + mlane;

#define RDSET(FA, FB, T)                                                     \
    {                                                                        \
        const ushort* lA = As + ((T) & 3) * 8192;                            \
        const ushort* lB = Bs + ((T) & 3) * 8192;                            \
        _Pragma("unroll")                                                    \
        for (int f_ = 0; f_ < 8; ++f_)                                       \
            FA[f_] = *(const bf16x8*)(lA + (arow + f_ * 16) * 32 + oswz);    \
        _Pragma("unroll")                                                    \
        for (int g_ = 0; g_ < 4; ++g_)                                       \
            FB[g_] = *(const bf16x8*)(lB + (brow + g_ * 16) * 32 + oswz);    \
    }

#define MMSET(FA, FB)                                                        \
    __builtin_amdgcn_s_setprio(1);                                           \
    _Pragma("unroll")                                                        \
    for (int f_ = 0; f_ < 8; ++f_) {                                         \
        _Pragma("unroll")                                                    \
        for (int g_ = 0; g_ < 4; ++g_) {                                     \
            acc[f_][g_] = __builtin_amdgcn_mfma_f32_16x16x32_bf16(           \
                FA[f_], FB[g_], acc[f_][g_], 0, 0, 0);                       \
        }                                                                    \
    }                                                                        \
    __builtin_amdgcn_s_setprio(0);

#define VMW(T)                                                               \
    if ((T) + 1 < NT) { asm volatile("s_waitcnt vmcnt(4)" ::: "memory"); }   \
    else              { asm volatile("s_waitcnt vmcnt(0)" ::: "memory"); }

    // prologue: stage tiles 0,1 (8 loads in flight)
    stage(0); stage(1);
    // t = 0: no MFMA yet
    VMW(0)
    __builtin_amdgcn_s_barrier();
    RDSET(fa0, fb0, 0)
    if (2 < NT) stage(2);
    // t = 1
    VMW(1)
    __builtin_amdgcn_s_barrier();
    RDSET(fa1, fb1, 1)
    if (3 < NT) stage(3);
    MMSET(fa0, fb0)
    // steady state, pair-unrolled for static register-set indices
    for (int u = 1; u < (NT >> 1); ++u) {
        const int te = 2 * u;
        VMW(te)
        __builtin_amdgcn_s_barrier();
        RDSET(fa0, fb0, te)
        if (te + 2 < NT) stage(te + 2);
        MMSET(fa1, fb1)
        const int to = te + 1;
        VMW(to)
        __builtin_amdgcn_s_barrier();
        RDSET(fa1, fb1, to)
        if (to + 2 < NT) stage(to + 2);
        MMSET(fa0, fb0)
    }
    // epilogue MFMA: tile NT-1 (odd since NT even) lives in set 1
    MMSET(fa1, fb1)
#undef RDSET
#undef MMSET
#undef VMW

    // epilogue: 16x16 C/D layout (harness-verified): col=mlane, row=quad*4+r
    const int cbase = n0 + wn * 64 + mlane;
#pragma unroll
    for (int f = 0; f < 8; ++f) {
#pragma unroll
        for (int r = 0; r < 4; ++r) {
            const int row = m0 + wm * 128 + f * 16 + quad * 4 + r;
            const size_t ro = (size_t)row * N;
#pragma unroll
            for (int g = 0; g < 4; ++g) {
                const int col = cbase + g * 16;
                const float av = acc[f][g][r];
                float o;
                if constexpr (EPI == 0) {
                    o = av;
                } else if constexpr (EPI == 2) {
                    o = aux1[ro + col] + sigmoidf_(av + bias[col]) * __bfloat162float(aux2[ro + col]);
                } else if constexpr (EPI == 3) {
                    const float tt = av + bias[col];
                    o = tt * sigmoidf_(tt);
                } else {  // 4
                    o = av + bias[col] + aux1[ro + col];
                }
                if constexpr (__is_same(CT, float)) C[ro + col] = o;
                else                                C[ro + col] = __float2bfloat16(o);
            }
        }
    }
}

// ---------------------------------------------------------------------------
// Fused: depthwise causal conv(4) + bias + SiLU + memory injection + 16-tap
// complex FIR + per-head coupling -> eig (fp32 out) + eig_bf (bf16 operand).
// ---------------------------------------------------------------------------
#define TCH 256
#define BROWS (TCH + TAPS + 2)   // beta rows: t in [t0-18, t0+255] = 274
#define UROWS (TCH + TAPS - 1)   // u rows:    t in [t0-15, t0+255] = 271

__global__ __launch_bounds__(256) void cfc_kernel(const float* __restrict__ beta,
                                                  const float* __restrict__ mgp,
                                                  const float* __restrict__ conv_w,
                                                  const float* __restrict__ conv_b,
                                                  const float* __restrict__ log_decay,
                                                  const float* __restrict__ freq,
                                                  const float* __restrict__ coup,
                                                  float* __restrict__ eig,
                                                  __hip_bfloat16* __restrict__ eig_bf) {
    const int b = blockIdx.z, h = blockIdx.y, t0 = blockIdx.x * TCH;
    const int tid = threadIdx.x;

    __shared__ float sbeta[BROWS * 32];       // col cg: cg<16 -> real ch, else imag
    __shared__ float su[UROWS * 33];
    __shared__ float str[16 * TAPS], sti[16 * TAPS];
    __shared__ float scoup[16 * 16];
    __shared__ float scw[32 * 4], scb[32];

    auto chan = [&](int cg) { return (cg < 16) ? (h * 16 + cg) : (128 + h * 16 + cg - 16); };

    for (int idx = tid; idx < BROWS * 32; idx += 256) {
        const int r = idx >> 5, cg = idx & 31;
        const int t = t0 - (TAPS + 2) + r;
        sbeta[idx] = (t >= 0) ? beta[((size_t)b * Tn + t) * TWOK + chan(cg)] : 0.f;
    }
    for (int idx = tid; idx < UROWS * 32; idx += 256) {
        const int r = idx >> 5, cg = idx & 31;
        const int t = t0 - (TAPS - 1) + r;
        su[r * 33 + cg] = (t >= 0) ? mgp[((size_t)b * Tn + t) * TWOK + chan(cg)] : 0.f;
    }
    if (tid < 128) scw[tid] = conv_w[chan(tid >> 2) * 4 + (tid & 3)];
    else if (tid < 160) scb[tid - 128] = conv_b[chan(tid - 128)];
    scoup[tid] = coup[h * 256 + tid];
    {
        const int k = tid >> 4, d = tid & (TAPS - 1);
        const float mag = sigmoidf_(log_decay[h * 16 + k]);
        const float f = freq[h * 16 + k];
        const float p = powf(mag, (float)d);
        str[k * TAPS + d] = p * cosf(d * f);
        sti[k * TAPS + d] = p * sinf(d * f);
    }
    __syncthreads();

    for (int idx = tid; idx < UROWS * 32; idx += 256) {
        const int r = idx >> 5, cg = idx & 31;
        const int rb = r + 3;
        float v = sbeta[(rb - 3) * 32 + cg] * scw[cg * 4 + 0] +
                  sbeta[(rb - 2) * 32 + cg] * scw[cg * 4 + 1] +
                  sbeta[(rb - 1) * 32 + cg] * scw[cg * 4 + 2] +
                  sbeta[(rb - 0) * 32 + cg] * scw[cg * 4 + 3] + scb[cg];
        v = v * sigmoidf_(v);
        su[r * 33 + cg] += v;
    }
    __syncthreads();

    const int ru = tid + (TAPS - 1);
    float orr[16], oii[16];
#pragma unroll
    for (int j = 0; j < 16; ++j) { orr[j] = 0.f; oii[j] = 0.f; }
#pragma unroll 4
    for (int k = 0; k < 16; ++k) {
        float accr = 0.f, acci = 0.f;
#pragma unroll
        for (int d = 0; d < TAPS; ++d) {
            const float ur = su[(ru - d) * 33 + k];
            const float ui = su[(ru - d) * 33 + 16 + k];
            const float lr = str[k * TAPS + d], li = sti[k * TAPS + d];
            accr += lr * ur - li * ui;
            acci += lr * ui + li * ur;
        }
#pragma unroll
        for (int j = 0; j < 16; ++j) {
            orr[j] += scoup[j * 16 + k] * accr;
            oii[j] += scoup[j * 16 + k] * acci;
        }
    }
    const size_t base = ((size_t)b * Tn + t0 + tid) * TWOK + h * 16;
    float4* er = (float4*)(eig + base);
    float4* ei = (float4*)(eig + base + Kn);
#pragma unroll
    for (int q = 0; q < 4; ++q) {
        er[q] = make_float4(orr[4 * q], orr[4 * q + 1], orr[4 * q + 2], orr[4 * q + 3]);
        ei[q] = make_float4(oii[4 * q], oii[4 * q + 1], oii[4 * q + 2], oii[4 * q + 3]);
    }
#pragma unroll
    for (int j = 0; j < 16; ++j) {
        eig_bf[base + j] = __float2bfloat16(orr[j]);
        eig_bf[base + Kn + j] = __float2bfloat16(oii[j]);
    }
}

// ---------------------------------------------------------------------------
extern "C" void kernel_launch(void* const* d_in, const int* in_sizes, int n_in,
                              void* d_out, int out_size, void* d_ws, size_t ws_size,
                              hipStream_t stream) {
    const float* x          = (const float*)d_in[0];
    const float* prev_eig   = (const float*)d_in[1];
    const float* in_proj_w  = (const float*)d_in[2];
    const float* conv_w     = (const float*)d_in[3];
    const float* conv_b     = (const float*)d_in[4];
    const float* mem_gate   = (const float*)d_in[5];
    const float* mem_proj_w = (const float*)d_in[6];
    const float* log_decay  = (const float*)d_in[7];
    const float* frequency  = (const float*)d_in[8];
    const float* coupling   = (const float*)d_in[9];
    const float* out_proj_w = (const float*)d_in[10];
    const float* gate_w     = (const float*)d_in[11];
    const float* gate_b     = (const float*)d_in[12];
    const float* mlp_w1     = (const float*)d_in[13];
    const float* mlp_b1     = (const float*)d_in[14];
    const float* mlp_w2     = (const float*)d_in[15];
    const float* mlp_b2     = (const float*)d_in[16];
    const float* n1_g       = (const float*)d_in[17];
    const float* n1_b       = (const float*)d_in[18];
    const float* n2_g       = (const float*)d_in[19];
    const float* n2_b       = (const float*)d_in[20];

    float* out = (float*)d_out;                     // x2 [16384,1024]
    float* eig = out + (size_t)NROW * Dn;           // eig [16384,256] fp32

    char* wsb = (char*)d_ws;
    const size_t MB = 1 << 20;
    const bool bigws = ws_size >= 252 * MB;

    float* x1    = (float*)(wsb + 0);               // 64MB, live step8..end
    float* beta  = (float*)(wsb + 0);               //  alias, live 2-4
    float* mgp   = (float*)(wsb + 16 * MB);         //  live 3-4
    __hip_bfloat16 *h1, *eig_bf, *peig_bf, *xn_bf, *y_bf, *w1_bf, *w2_bf,
                   *gate_bf, *inpj_bf, *outpj_bf, *mempj_bf;
    if (bigws) {
        h1       = (__hip_bfloat16*)(wsb + 64 * MB);    // step 7 oproj (32MB) then step10 h1 (128MB)
        xn_bf    = (__hip_bfloat16*)(wsb + 192 * MB);   // live 1..8
        y_bf     = (__hip_bfloat16*)(wsb + 192 * MB);   //  alias (written step 9)
        w1_bf    = (__hip_bfloat16*)(wsb + 224 * MB);
        w2_bf    = (__hip_bfloat16*)(wsb + 232 * MB);
        gate_bf  = (__hip_bfloat16*)(wsb + 240 * MB);
        inpj_bf  = (__hip_bfloat16*)(wsb + 242 * MB);
        outpj_bf = (__hip_bfloat16*)(wsb + 242 * MB + 512 * 1024);
        mempj_bf = (__hip_bfloat16*)(wsb + 243 * MB);
        peig_bf  = (__hip_bfloat16*)(wsb + 244 * MB);   // live step 3 only
        eig_bf   = (__hip_bfloat16*)(wsb + 244 * MB);   //  alias (written step 4-6)
    } else {
        h1       = (__hip_bfloat16*)(wsb + 64 * MB);    // step 7 oproj (32MB) / step10 chunk h1
        eig_bf   = (__hip_bfloat16*)(wsb + 96 * MB);
        peig_bf  = (__hip_bfloat16*)(wsb + 104 * MB);
        xn_bf    = (__hip_bfloat16*)(wsb + 128 * MB);
        y_bf     = (__hip_bfloat16*)(wsb + 160 * MB);
        w1_bf    = (__hip_bfloat16*)(wsb + 192 * MB);
        w2_bf    = (__hip_bfloat16*)(wsb + 200 * MB);
        gate_bf  = (__hip_bfloat16*)(wsb + 208 * MB);
        inpj_bf  = (__hip_bfloat16*)(wsb + 210 * MB);
        outpj_bf = (__hip_bfloat16*)(wsb + 210 * MB + 512 * 1024);
        mempj_bf = (__hip_bfloat16*)(wsb + 211 * MB);
    }

    // 0) all weight/activation fp32->bf16 casts in ONE launch
    multicast_kernel<<<dim3(2048), dim3(256), 0, stream>>>(
        in_proj_w,  inpj_bf,
        mem_proj_w, mempj_bf,
        out_proj_w, outpj_bf,
        gate_w,     gate_bf,
        mlp_w1,     w1_bf,
        mlp_w2,     w2_bf,
        prev_eig,   peig_bf);

    // 1) xn = LN1(x) -> bf16
    ln_kernel<<<dim3(NROW), dim3(256), 0, stream>>>(x, n1_g, n1_b, xn_bf);
    // 2) beta = xn @ in_proj^T  [16384,256] fp32
    gemm_bf<0, float><<<dim3(2, 128), dim3(256), 0, stream>>>(
        (const ushort*)xn_bf, (const ushort*)inpj_bf, beta, NROW, TWOK, Dn, nullptr);
    // 3) mgp = sigmoid(mem_gate) * (prev_eig @ mem_proj^T)
    gemm_bf<1, float><<<dim3(2, 128), dim3(256), 0, stream>>>(
        (const ushort*)peig_bf, (const ushort*)mempj_bf, mgp, NROW, TWOK, TWOK, mem_gate);
    // 4-6) fused conv + SiLU + mem + FIR + coupling -> eig, eig_bf
    cfc_kernel<<<dim3(Tn / TCH, Hn, Bn), dim3(256), 0, stream>>>(
        beta, mgp, conv_w, conv_b, log_decay, frequency, coupling, eig, eig_bf);
    // 7) oproj = eig @ out_proj^T  [16384,1024] -> bf16 temp in h1 region
    gemmP<0, __hip_bfloat16><<<dim3(4, 64), dim3(512), 0, stream>>>(
        (const ushort*)eig_bf, (const ushort*)outpj_bf, h1, Dn, TWOK,
        nullptr, nullptr, nullptr, 1);
    // 8) x1 = x + sigmoid(xn@gate_w^T + gate_b) * oproj
    gemmP<2, float><<<dim3(4, 64), dim3(512), 0, stream>>>(
        (const ushort*)xn_bf, (const ushort*)gate_bf, x1, Dn, Dn,
        gate_b, x, h1, 1);
    // 9) y = LN2(x1) -> bf16
    ln_kernel<<<dim3(NROW), dim3(256), 0, stream>>>(x1, n2_g, n2_b, y_bf);
    // 10) MLP via gemmP
    if (bigws) {
        gemmP<3, __hip_bfloat16><<<dim3(16, 64), dim3(512), 0, stream>>>(
            (const ushort*)y_bf, (const ushort*)w1_bf, h1, Mmlp, Dn,
            mlp_b1, nullptr, nullptr, 2);
        gemmP<4, float><<<dim3(4, 64), dim3(512), 0, stream>>>(
            (const ushort*)h1, (const ushort*)w2_bf, out, Dn, Mmlp,
            mlp_b2, x1, nullptr, 1);
    } else {
        for (int ck = 0; ck < 2; ++ck) {
            const size_t roff = (size_t)ck * 8192 * Dn;
            gemmP<3, __hip_bfloat16><<<dim3(16, 32), dim3(512), 0, stream>>>(
                (const ushort*)(y_bf + roff), (const ushort*)w1_bf, h1, Mmlp, Dn,
                mlp_b1, nullptr, nullptr, 2);
            gemmP<4, float><<<dim3(8, 32), dim3(512), 0, stream>>>(
                (const ushort*)h1, (const ushort*)w2_bf, out + roff, Dn, Mmlp,
                mlp_b2, x1 + roff, nullptr, 1);
        }
    }
}